// Round 3
// baseline (1381.385 us; speedup 1.0000x reference)
//
#include <hip/hip_runtime.h>
#include <hip/hip_bf16.h>

#define SEQ 2048
#define NHEAD 24     // 3*H
#define CDIM 32
#define VDIM 128
#define TI 32
#define TJ 64

// Static device-global scratch (no ws_size dependence).
__device__ float g_kk[(size_t)SEQ * NHEAD * CDIM];    // [S][24][32]
__device__ float g_qq[(size_t)SEQ * NHEAD * CDIM];    // [S][24][32]
__device__ float g_vv[(size_t)SEQ * NHEAD * VDIM];    // [S][24][128]

// ---------- values projection: g_vv[i*3072 + g*128 + d] = nodes[i,:].w_values[o,:] + b ----------
__global__ __launch_bounds__(256) void k_val(const float* __restrict__ nodes,
                                             const float* __restrict__ w,
                                             const float* __restrict__ b) {
  __shared__ __align__(16) float n_sh[16][128];
  const int tx = threadIdx.x;
  const int o  = blockIdx.x * 256 + tx;     // output column 0..3071
  const int i0 = blockIdx.y * 16;           // row tile
  for (int idx = tx; idx < 16 * 128 / 4; idx += 256) {
    int r = idx >> 5, c4 = idx & 31;
    *(float4*)&n_sh[r][c4 * 4] = ((const float4*)nodes)[((i0 + r) * 128 >> 2) + c4];
  }
  __syncthreads();
  float acc[16];
  const float bias = b[o];
#pragma unroll
  for (int r = 0; r < 16; ++r) acc[r] = bias;
  const float4* w4 = (const float4*)(w + (size_t)o * 128);
  for (int d4 = 0; d4 < 32; ++d4) {
    float4 wv = w4[d4];
#pragma unroll
    for (int r = 0; r < 16; ++r) {
      float4 nv = *(const float4*)&n_sh[r][d4 * 4];
      acc[r] += nv.x * wv.x + nv.y * wv.y + nv.z * wv.z + nv.w * wv.w;
    }
  }
  for (int r = 0; r < 16; ++r) g_vv[(size_t)(i0 + r) * 3072 + o] = acc[r];
}

// ---------- k/q projections (nodes, circular-pos, rot branches) ----------
__global__ __launch_bounds__(256) void k_kq(const float* __restrict__ nodes,
                                            const float* __restrict__ pos,
                                            const float* __restrict__ rot,
                                            const float* __restrict__ w_n,
                                            const float* __restrict__ b_n,
                                            const float* __restrict__ w_p,
                                            const float* __restrict__ b_p,
                                            const float* __restrict__ w_r) {
  const int i = blockIdx.x;
  const int tx = threadIdx.x;
  __shared__ float n_sh[128];
  __shared__ float pf[6];
  __shared__ float r_sh[4];
  if (tx < 128) n_sh[tx] = nodes[i * 128 + tx];
  if (tx >= 128 && tx < 131) {
    int t = tx - 128;
    float p = pos[i * 3 + t];
    pf[t]     = cosf(6.283185307179586f * p);
    pf[t + 3] = sinf(6.283185307179586f * p);
  }
  if (tx >= 132 && tx < 136) r_sh[tx - 132] = rot[i * 4 + (tx - 132)];
  __syncthreads();
  for (int o = tx; o < 512; o += 256) {
    const int h = o >> 6;
    const int c0 = o & 63;
    const int c = c0 & 31;
    float* dst = (c0 < 32) ? g_kk : g_qq;   // split: first 32 chans -> k, last 32 -> q
    float a = b_n[o];
    for (int d = 0; d < 128; ++d) a += n_sh[d] * w_n[o * 128 + d];
    dst[((size_t)i * NHEAD + h) * CDIM + c] = a;            // nodes -> heads 0..7
    float ap = b_p[o];
    for (int d = 0; d < 6; ++d) ap += pf[d] * w_p[o * 6 + d];
    dst[((size_t)i * NHEAD + 8 + h) * CDIM + c] = ap;       // pos -> heads 8..15
    float ar = 0.f;
    for (int d = 0; d < 4; ++d) ar += r_sh[d] * w_r[o * 4 + d];
    dst[((size_t)i * NHEAD + 16 + h) * CDIM + c] = ar;      // rot -> heads 16..23
  }
}

// ---------- zero the output (harness poisons d_out before every launch) ----------
__global__ __launch_bounds__(256) void k_zero(float* __restrict__ out) {
  out[blockIdx.x * 256 + threadIdx.x] = 0.f;
}

// ---------- flash-style attention: block = (head g, i-tile of 32) ----------
__global__ __launch_bounds__(256, 2) void k_attn(float* __restrict__ outf) {
  const int g  = blockIdx.x;          // 0..23
  const int i0 = blockIdx.y * TI;
  const int tx = threadIdx.x;
  const int i_loc = tx >> 3;          // 0..31
  const int sub   = tx & 7;           // d-chunk / j-chunk id
  const bool is_rot = (g >= 16);

  __shared__ float k_sh[TI][33];
  __shared__ float q_sh[TJ][33];
  __shared__ __align__(16) float v_sh[TJ][128];
  __shared__ float p_sh[TI][TJ + 1];

  for (int idx = tx; idx < TI * CDIM; idx += 256) {
    int r = idx >> 5, c = idx & 31;
    k_sh[r][c] = g_kk[(((size_t)(i0 + r)) * NHEAD + g) * CDIM + c];
  }
  __syncthreads();
  float k_reg[32];
#pragma unroll
  for (int c = 0; c < 32; ++c) k_reg[c] = k_sh[i_loc][c];   // broadcast (same addr per wave-row)

  float m_run = -1e30f, l_run = 0.f;
  float o_acc[16];
#pragma unroll
  for (int z = 0; z < 16; ++z) o_acc[z] = 0.f;

  for (int j0 = 0; j0 < SEQ; j0 += TJ) {
    __syncthreads();  // prev PV reads done before restaging
    for (int idx = tx; idx < TJ * CDIM; idx += 256) {
      int r = idx >> 5, c = idx & 31;
      q_sh[r][c] = g_qq[(((size_t)(j0 + r)) * NHEAD + g) * CDIM + c];
    }
    const float4* vg = (const float4*)g_vv;
    for (int idx = tx; idx < TJ * 32; idx += 256) {  // TJ*128/4 float4s
      int r = idx >> 5, d4 = idx & 31;
      ((float4*)&v_sh[r][0])[d4] = vg[(((size_t)(j0 + r)) * NHEAD + g) * 32 + d4];
    }
    __syncthreads();

    // logits: 8 per thread, j = sub*8 + jj
    float lg[8];
#pragma unroll
    for (int jj = 0; jj < 8; ++jj) {
      const float* qrow = &q_sh[sub * 8 + jj][0];
      float a = 0.f;
#pragma unroll
      for (int c = 0; c < 32; ++c) a += k_reg[c] * qrow[c];
      if (is_rot) a = a * a;
      lg[jj] = a;
    }
    float tmax = lg[0];
#pragma unroll
    for (int jj = 1; jj < 8; ++jj) tmax = fmaxf(tmax, lg[jj]);
    tmax = fmaxf(tmax, __shfl_xor(tmax, 1));
    tmax = fmaxf(tmax, __shfl_xor(tmax, 2));
    tmax = fmaxf(tmax, __shfl_xor(tmax, 4));
    const float m_new = fmaxf(m_run, tmax);
    const float scale = __expf(m_run - m_new);
    float psum = 0.f;
#pragma unroll
    for (int jj = 0; jj < 8; ++jj) {
      float p = __expf(lg[jj] - m_new);
      p_sh[i_loc][sub * 8 + jj] = p;
      psum += p;
    }
    psum += __shfl_xor(psum, 1);
    psum += __shfl_xor(psum, 2);
    psum += __shfl_xor(psum, 4);
    l_run = l_run * scale + psum;
    m_run = m_new;
#pragma unroll
    for (int z = 0; z < 16; ++z) o_acc[z] *= scale;
    __syncthreads();

    // PV: o_acc[d = sub*16 + z] += p[i_loc][j] * v[j][d]
#pragma unroll 4
    for (int j = 0; j < TJ; ++j) {
      const float p = p_sh[i_loc][j];
      const float4* vrow = (const float4*)&v_sh[j][sub * 16];
      float4 v0 = vrow[0], v1 = vrow[1], v2 = vrow[2], v3 = vrow[3];
      o_acc[0]  += p * v0.x; o_acc[1]  += p * v0.y; o_acc[2]  += p * v0.z; o_acc[3]  += p * v0.w;
      o_acc[4]  += p * v1.x; o_acc[5]  += p * v1.y; o_acc[6]  += p * v1.z; o_acc[7]  += p * v1.w;
      o_acc[8]  += p * v2.x; o_acc[9]  += p * v2.y; o_acc[10] += p * v2.z; o_acc[11] += p * v2.w;
      o_acc[12] += p * v3.x; o_acc[13] += p * v3.y; o_acc[14] += p * v3.z; o_acc[15] += p * v3.w;
    }
  }

  const float inv = 1.f / l_run;
  const int i = i0 + i_loc;
#pragma unroll
  for (int z = 0; z < 16; ++z)
    atomicAdd(&outf[(size_t)i * VDIM + sub * 16 + z], o_acc[z] * inv);
}

extern "C" void kernel_launch(void* const* d_in, const int* in_sizes, int n_in,
                              void* d_out, int out_size, void* d_ws, size_t ws_size,
                              hipStream_t stream) {
  const float* nodes = (const float*)d_in[0];
  const float* pos   = (const float*)d_in[1];
  const float* rot   = (const float*)d_in[2];
  const float* w_n   = (const float*)d_in[3];
  const float* b_n   = (const float*)d_in[4];
  const float* w_p   = (const float*)d_in[5];
  const float* b_p   = (const float*)d_in[6];
  const float* w_r   = (const float*)d_in[7];
  const float* w_v   = (const float*)d_in[8];
  const float* b_v   = (const float*)d_in[9];
  float* out = (float*)d_out;

  k_zero<<<dim3((SEQ * VDIM) / 256), 256, 0, stream>>>(out);
  k_val<<<dim3(12, 128), 256, 0, stream>>>(nodes, w_v, b_v);
  k_kq<<<dim3(SEQ), 256, 0, stream>>>(nodes, pos, rot, w_n, b_n, w_p, b_p, w_r);
  k_attn<<<dim3(NHEAD, SEQ / TI), 256, 0, stream>>>(out);
}

// Round 4
// 354.140 us; speedup vs baseline: 3.9007x; 3.9007x over previous
//
#include <hip/hip_runtime.h>
#include <hip/hip_bf16.h>

#define SEQ 2048
#define NHEAD 24     // 3*H
#define CDIM 32
#define VDIM 128

typedef short bf16x8 __attribute__((ext_vector_type(8)));
typedef float f32x4 __attribute__((ext_vector_type(4)));

// Frag-packed operand buffers (bf16 as ushort).
// K A-frags + Q B-frags, hi/lo split: [g][blk16(128)][part(2)][lane(64)][e(8)]
__device__ unsigned short g_kkp[(size_t)24 * 128 * 2 * 64 * 8];
__device__ unsigned short g_qqp[(size_t)24 * 128 * 2 * 64 * 8];
// V B-frags: [g][jb32(64)][db16(8)][lane(64)][e(8)]
__device__ unsigned short g_vvp[(size_t)24 * 64 * 8 * 64 * 8];

__device__ __forceinline__ unsigned short f2b(float x) {   // RNE f32->bf16
  union { float f; unsigned u; } v; v.f = x;
  unsigned r = v.u + 0x7FFF + ((v.u >> 16) & 1);
  return (unsigned short)(r >> 16);
}
__device__ __forceinline__ float b2f(unsigned short u) {
  union { unsigned u32; float f; } x; x.u32 = ((unsigned)u) << 16; return x.f;
}

// ---------- values projection -> V B-frags ----------
__global__ __launch_bounds__(256) void k_val(const float* __restrict__ nodes,
                                             const float* __restrict__ w,
                                             const float* __restrict__ b) {
  __shared__ __align__(16) float n_sh[16][128];
  const int tx = threadIdx.x;
  const int o  = blockIdx.x * 256 + tx;     // output column 0..3071
  const int i0 = blockIdx.y * 16;           // row tile (16 consecutive j)
  for (int idx = tx; idx < 16 * 128 / 4; idx += 256) {
    int r = idx >> 5, c4 = idx & 31;
    *(float4*)&n_sh[r][c4 * 4] = ((const float4*)nodes)[((i0 + r) * 128 >> 2) + c4];
  }
  __syncthreads();
  float acc[16];
  const float bias = b[o];
#pragma unroll
  for (int r = 0; r < 16; ++r) acc[r] = bias;
  const float4* w4 = (const float4*)(w + (size_t)o * 128);
  for (int d4 = 0; d4 < 32; ++d4) {
    float4 wv = w4[d4];
#pragma unroll
    for (int r = 0; r < 16; ++r) {
      float4 nv = *(const float4*)&n_sh[r][d4 * 4];
      acc[r] += nv.x * wv.x + nv.y * wv.y + nv.z * wv.z + nv.w * wv.w;
    }
  }
  // pack to V B-frag layout: B[n=d&15][k=j&31], lane=((j&31)>>3)*16+(d&15), e=j&7
  const int g  = o >> 7, d = o & 127;
  const int jb = i0 >> 5;                 // i0 is mult of 16 -> all rows in one jb
  const int db = d >> 4, nn = d & 15;
  const int khb = (i0 & 31) >> 3;         // 0 or 2
#pragma unroll
  for (int half = 0; half < 2; ++half) {
    bf16x8 pk;
#pragma unroll
    for (int e = 0; e < 8; ++e) pk[e] = (short)f2b(acc[half * 8 + e]);
    ((bf16x8*)g_vvp)[((size_t)(g * 64 + jb) * 8 + db) * 64 + (khb + half) * 16 + nn] = pk;
  }
}

// ---------- k/q projections -> A/B frags with hi/lo split ----------
__device__ __forceinline__ void store_kq(unsigned short* dst, int g, int blk,
                                         int lane, int e, float v) {
  unsigned short hi = f2b(v);
  unsigned short lo = f2b(v - b2f(hi));
  size_t base = (((size_t)(g * 128 + blk) * 2) * 64 + lane) * 8 + e;
  dst[base] = hi;
  dst[base + 64 * 8] = lo;
}

__global__ __launch_bounds__(256) void k_kq(const float* __restrict__ nodes,
                                            const float* __restrict__ pos,
                                            const float* __restrict__ rot,
                                            const float* __restrict__ w_n,
                                            const float* __restrict__ b_n,
                                            const float* __restrict__ w_p,
                                            const float* __restrict__ b_p,
                                            const float* __restrict__ w_r) {
  const int i = blockIdx.x;
  const int tx = threadIdx.x;
  __shared__ float n_sh[128];
  __shared__ float pf[6];
  __shared__ float r_sh[4];
  if (tx < 128) n_sh[tx] = nodes[i * 128 + tx];
  if (tx >= 128 && tx < 131) {
    int t = tx - 128;
    float p = pos[i * 3 + t];
    pf[t]     = cosf(6.283185307179586f * p);
    pf[t + 3] = sinf(6.283185307179586f * p);
  }
  if (tx >= 132 && tx < 136) r_sh[tx - 132] = rot[i * 4 + (tx - 132)];
  __syncthreads();
  const int m = i & 15, blk = i >> 4;
  for (int o = tx; o < 512; o += 256) {
    const int h = o >> 6;
    const int c = o & 31;
    unsigned short* dst = ((o & 63) < 32) ? g_kkp : g_qqp;  // k->A, q->B (same formula)
    const int lane = ((c >> 3) << 4) + m, e = c & 7;
    float a = b_n[o];
    for (int d = 0; d < 128; ++d) a += n_sh[d] * w_n[o * 128 + d];
    store_kq(dst, h, blk, lane, e, a);            // nodes -> heads 0..7
    float ap = b_p[o];
    for (int d = 0; d < 6; ++d) ap += pf[d] * w_p[o * 6 + d];
    store_kq(dst, 8 + h, blk, lane, e, ap);       // pos -> heads 8..15
    float ar = 0.f;
    for (int d = 0; d < 4; ++d) ar += r_sh[d] * w_r[o * 4 + d];
    store_kq(dst, 16 + h, blk, lane, e, ar);      // rot -> heads 16..23
  }
}

// ---------- zero output ----------
__global__ __launch_bounds__(256) void k_zero(float* __restrict__ out) {
  out[blockIdx.x * 256 + threadIdx.x] = 0.f;
}

// ---------- MFMA flash attention: block = (head g, 32-row i-tile), 4 waves ----------
__global__ __launch_bounds__(256) void k_attn(float* __restrict__ out) {
  const int g  = blockIdx.x;           // 0..23
  const int it = blockIdx.y;           // 0..63
  const int tx = threadIdx.x;
  const int w = tx >> 6, lane = tx & 63;
  const int qd = lane >> 4, n = lane & 15;

  __shared__ __align__(16) unsigned short p_frag[2 * 2 * 64 * 8];  // [ib][chunk][lane][e]
  __shared__ float wmax[4][32];
  __shared__ float wsum[4][32];
  __shared__ __align__(16) float mnew_s[32];
  __shared__ __align__(16) float alpha_s[32];
  __shared__ __align__(16) float mrun_s[32];
  __shared__ __align__(16) float lrun_s[32];

  if (tx < 32) { mrun_s[tx] = -1e30f; lrun_s[tx] = 0.f; }

  // persistent K A-frags: [ib][part]
  const bf16x8* kp = (const bf16x8*)g_kkp + (size_t)(g * 128 + it * 2) * 2 * 64;
  bf16x8 ka[2][2];
#pragma unroll
  for (int ib = 0; ib < 2; ++ib)
#pragma unroll
    for (int part = 0; part < 2; ++part)
      ka[ib][part] = kp[(ib * 2 + part) * 64 + lane];

  f32x4 oacc[2][2];   // [ib][dtl]
#pragma unroll
  for (int a = 0; a < 2; ++a)
#pragma unroll
    for (int bb = 0; bb < 2; ++bb)
#pragma unroll
      for (int r = 0; r < 4; ++r) oacc[a][bb][r] = 0.f;

  const int chunk_w = w >> 1, jbl_w = w & 1;
  const int pin = (lane & 56) | ((lane ^ (lane >> 3)) & 7);  // XOR swizzle (read)
  const bool is_rot = (g >= 16);

  __syncthreads();

  for (int jt = 0; jt < 32; ++jt) {
    // --- S = K·Q^T (split bf16: hihi + hilo + lohi) for this wave's 16-j block
    const bf16x8* qp = (const bf16x8*)g_qqp + (size_t)(g * 128 + jt * 4 + w) * 2 * 64;
    bf16x8 qhi = qp[lane], qlo = qp[64 + lane];
    f32x4 S[2];
#pragma unroll
    for (int ib = 0; ib < 2; ++ib) {
      f32x4 acc = {0.f, 0.f, 0.f, 0.f};
      acc = __builtin_amdgcn_mfma_f32_16x16x32_bf16(ka[ib][0], qhi, acc, 0, 0, 0);
      acc = __builtin_amdgcn_mfma_f32_16x16x32_bf16(ka[ib][0], qlo, acc, 0, 0, 0);
      acc = __builtin_amdgcn_mfma_f32_16x16x32_bf16(ka[ib][1], qhi, acc, 0, 0, 0);
      S[ib] = acc;
    }
    if (is_rot) {
#pragma unroll
      for (int ib = 0; ib < 2; ++ib)
#pragma unroll
        for (int r = 0; r < 4; ++r) S[ib][r] *= S[ib][r];
    }
    // --- per-row max over the 16 j-lanes
    float rm[2][4];
#pragma unroll
    for (int ib = 0; ib < 2; ++ib)
#pragma unroll
      for (int r = 0; r < 4; ++r) {
        float v = S[ib][r];
        v = fmaxf(v, __shfl_xor(v, 1));
        v = fmaxf(v, __shfl_xor(v, 2));
        v = fmaxf(v, __shfl_xor(v, 4));
        v = fmaxf(v, __shfl_xor(v, 8));
        rm[ib][r] = v;
      }
    if (n < 8) {
      float v = rm[0][0];
      v = (n == 1) ? rm[0][1] : v; v = (n == 2) ? rm[0][2] : v; v = (n == 3) ? rm[0][3] : v;
      v = (n == 4) ? rm[1][0] : v; v = (n == 5) ? rm[1][1] : v;
      v = (n == 6) ? rm[1][2] : v; v = (n == 7) ? rm[1][3] : v;
      wmax[w][(n >> 2) * 16 + qd * 4 + (n & 3)] = v;
    }
    __syncthreads();
    if (tx < 32) {
      float mo = mrun_s[tx];
      float mx = fmaxf(fmaxf(wmax[0][tx], wmax[1][tx]), fmaxf(wmax[2][tx], wmax[3][tx]));
      mx = fmaxf(mx, mo);
      mnew_s[tx] = mx;
      alpha_s[tx] = __expf(mo - mx);
      mrun_s[tx] = mx;
    }
    __syncthreads();
    const f32x4 mn0 = *(const f32x4*)&mnew_s[qd * 4];
    const f32x4 mn1 = *(const f32x4*)&mnew_s[16 + qd * 4];
    const f32x4 al0 = *(const f32x4*)&alpha_s[qd * 4];
    const f32x4 al1 = *(const f32x4*)&alpha_s[16 + qd * 4];
    // --- P = exp(S - m), stash bf16 A-frags in LDS, row-sums
    float rs[2][4];
#pragma unroll
    for (int ib = 0; ib < 2; ++ib)
#pragma unroll
      for (int r = 0; r < 4; ++r) {
        float p = __expf(S[ib][r] - (ib ? mn1[r] : mn0[r]));
        rs[ib][r] = p;
        int lanep = (jbl_w * 2 + (n >> 3)) * 16 + qd * 4 + r;
        int pp = (lanep & 56) | ((lanep ^ (lanep >> 3)) & 7);
        p_frag[((ib * 2 + chunk_w) * 64 + pp) * 8 + (n & 7)] = f2b(p);
      }
#pragma unroll
    for (int ib = 0; ib < 2; ++ib)
#pragma unroll
      for (int r = 0; r < 4; ++r) {
        float v = rs[ib][r];
        v += __shfl_xor(v, 1); v += __shfl_xor(v, 2);
        v += __shfl_xor(v, 4); v += __shfl_xor(v, 8);
        rs[ib][r] = v;
      }
    if (n < 8) {
      float v = rs[0][0];
      v = (n == 1) ? rs[0][1] : v; v = (n == 2) ? rs[0][2] : v; v = (n == 3) ? rs[0][3] : v;
      v = (n == 4) ? rs[1][0] : v; v = (n == 5) ? rs[1][1] : v;
      v = (n == 6) ? rs[1][2] : v; v = (n == 7) ? rs[1][3] : v;
      wsum[w][(n >> 2) * 16 + qd * 4 + (n & 3)] = v;
    }
    // --- rescale accumulators by alpha (rows follow C layout)
#pragma unroll
    for (int dtl = 0; dtl < 2; ++dtl)
#pragma unroll
      for (int r = 0; r < 4; ++r) {
        oacc[0][dtl][r] *= al0[r];
        oacc[1][dtl][r] *= al1[r];
      }
    __syncthreads();
    if (tx < 32)
      lrun_s[tx] = lrun_s[tx] * alpha_s[tx] +
                   wsum[0][tx] + wsum[1][tx] + wsum[2][tx] + wsum[3][tx];
    // --- PV: O += P(A-frags from LDS) x V(B-frags from global)
    const bf16x8* vp = (const bf16x8*)g_vvp + (size_t)(g * 64 + jt * 2) * 8 * 64;
#pragma unroll
    for (int chunk = 0; chunk < 2; ++chunk) {
      bf16x8 a0 = *(const bf16x8*)&p_frag[((0 * 2 + chunk) * 64 + pin) * 8];
      bf16x8 a1 = *(const bf16x8*)&p_frag[((1 * 2 + chunk) * 64 + pin) * 8];
#pragma unroll
      for (int dtl = 0; dtl < 2; ++dtl) {
        bf16x8 bfr = vp[(chunk * 8 + w * 2 + dtl) * 64 + lane];
        oacc[0][dtl] = __builtin_amdgcn_mfma_f32_16x16x32_bf16(a0, bfr, oacc[0][dtl], 0, 0, 0);
        oacc[1][dtl] = __builtin_amdgcn_mfma_f32_16x16x32_bf16(a1, bfr, oacc[1][dtl], 0, 0, 0);
      }
    }
  }
  __syncthreads();
  const f32x4 l0 = *(const f32x4*)&lrun_s[qd * 4];
  const f32x4 l1 = *(const f32x4*)&lrun_s[16 + qd * 4];
#pragma unroll
  for (int ib = 0; ib < 2; ++ib)
#pragma unroll
    for (int dtl = 0; dtl < 2; ++dtl)
#pragma unroll
      for (int r = 0; r < 4; ++r) {
        int i = it * 32 + ib * 16 + qd * 4 + r;
        int d = w * 32 + dtl * 16 + n;
        atomicAdd(&out[(size_t)i * VDIM + d], oacc[ib][dtl][r] / (ib ? l1[r] : l0[r]));
      }
}

extern "C" void kernel_launch(void* const* d_in, const int* in_sizes, int n_in,
                              void* d_out, int out_size, void* d_ws, size_t ws_size,
                              hipStream_t stream) {
  const float* nodes = (const float*)d_in[0];
  const float* pos   = (const float*)d_in[1];
  const float* rot   = (const float*)d_in[2];
  const float* w_n   = (const float*)d_in[3];
  const float* b_n   = (const float*)d_in[4];
  const float* w_p   = (const float*)d_in[5];
  const float* b_p   = (const float*)d_in[6];
  const float* w_r   = (const float*)d_in[7];
  const float* w_v   = (const float*)d_in[8];
  const float* b_v   = (const float*)d_in[9];
  float* out = (float*)d_out;

  k_zero<<<dim3((SEQ * VDIM) / 256), 256, 0, stream>>>(out);
  k_val<<<dim3(12, 128), 256, 0, stream>>>(nodes, w_v, b_v);
  k_kq<<<dim3(SEQ), 256, 0, stream>>>(nodes, pos, rot, w_n, b_n, w_p, b_p, w_r);
  k_attn<<<dim3(NHEAD, 64), 256, 0, stream>>>(out);
}

// Round 5
// 347.946 us; speedup vs baseline: 3.9701x; 1.0178x over previous
//
#include <hip/hip_runtime.h>
#include <hip/hip_bf16.h>
#include <math.h>

#define SEQ 2048
#define NHEAD 24     // 3*H
#define CDIM 32
#define VDIM 128

typedef short bf16x8 __attribute__((ext_vector_type(8)));
typedef float f32x4 __attribute__((ext_vector_type(4)));

#define L2E 1.44269504088896f        // log2(e): folded into K so exp2 == exp
#define SQRT_L2E 1.20112240878645f   // sqrt(log2 e): rot logits get squared

// Frag-packed operand buffers (bf16 as ushort).
// K B-frags + Q A-frags, hi/lo split: [g][blk16(128)][part(2)][lane(64)][e(8)]
__device__ unsigned short g_kkp[(size_t)24 * 128 * 2 * 64 * 8];
__device__ unsigned short g_qqp[(size_t)24 * 128 * 2 * 64 * 8];
// V B-frags: [g][jb32(64)][db16(8)][lane(64)][e(8)]
__device__ unsigned short g_vvp[(size_t)24 * 64 * 8 * 64 * 8];

__device__ __forceinline__ unsigned short f2b(float x) {   // RNE f32->bf16
  union { float f; unsigned u; } v; v.f = x;
  unsigned r = v.u + 0x7FFF + ((v.u >> 16) & 1);
  return (unsigned short)(r >> 16);
}
__device__ __forceinline__ float b2f(unsigned short u) {
  union { unsigned u32; float f; } x; x.u32 = ((unsigned)u) << 16; return x.f;
}
__device__ __forceinline__ unsigned pk2(float a, float b) {  // [lo=a, hi=b] bf16 pair
  __hip_bfloat162 t = __float22bfloat162_rn(float2{a, b});
  union { __hip_bfloat162 h; unsigned u; } c; c.h = t; return c.u;
}

// ---------- values projection -> V B-frags (validated round 4) ----------
__global__ __launch_bounds__(256) void k_val(const float* __restrict__ nodes,
                                             const float* __restrict__ w,
                                             const float* __restrict__ b) {
  __shared__ __align__(16) float n_sh[16][128];
  const int tx = threadIdx.x;
  const int o  = blockIdx.x * 256 + tx;     // output column 0..3071
  const int i0 = blockIdx.y * 16;           // row tile (16 consecutive j)
  for (int idx = tx; idx < 16 * 128 / 4; idx += 256) {
    int r = idx >> 5, c4 = idx & 31;
    *(float4*)&n_sh[r][c4 * 4] = ((const float4*)nodes)[((i0 + r) * 128 >> 2) + c4];
  }
  __syncthreads();
  float acc[16];
  const float bias = b[o];
#pragma unroll
  for (int r = 0; r < 16; ++r) acc[r] = bias;
  const float4* w4 = (const float4*)(w + (size_t)o * 128);
  for (int d4 = 0; d4 < 32; ++d4) {
    float4 wv = w4[d4];
#pragma unroll
    for (int r = 0; r < 16; ++r) {
      float4 nv = *(const float4*)&n_sh[r][d4 * 4];
      acc[r] += nv.x * wv.x + nv.y * wv.y + nv.z * wv.z + nv.w * wv.w;
    }
  }
  // pack to V B-frag layout: lane=((j&31)>>3)*16+(d&15), e=j&7
  const int g  = o >> 7, d = o & 127;
  const int jb = i0 >> 5;
  const int db = d >> 4, nn = d & 15;
  const int khb = (i0 & 31) >> 3;         // 0 or 2
#pragma unroll
  for (int half = 0; half < 2; ++half) {
    bf16x8 pk;
#pragma unroll
    for (int e = 0; e < 8; ++e) pk[e] = (short)f2b(acc[half * 8 + e]);
    ((bf16x8*)g_vvp)[((size_t)(g * 64 + jb) * 8 + db) * 64 + (khb + half) * 16 + nn] = pk;
  }
}

// ---------- k/q projections: LDS-staged compute + coalesced frag repack ----------
__device__ __forceinline__ void repack_store(const unsigned* __restrict__ res,
                                             int oh, int it16, int tx, int head_base) {
#pragma unroll
  for (int t2 = 0; t2 < 2; ++t2) {
    int cid = tx + t2 * 256;           // 0..511
    int hl  = cid >> 7;                // local head 0..3
    int kq  = (cid >> 6) & 1;          // 0=k 1=q
    int row = cid & 63;                // frag lane
    int m = row & 15, kb = row >> 4;
    int ob = hl * 64 + kq * 32 + kb * 8;
    bf16x8 hi, lo;
#pragma unroll
    for (int e = 0; e < 8; ++e) {
      unsigned pk = res[(ob + e) * 17 + m];
      hi[e] = (short)(pk >> 16);
      lo[e] = (short)(pk & 0xffff);
    }
    unsigned short* dst = kq ? g_qqp : g_kkp;
    size_t base = ((size_t)((head_base + oh * 4 + hl) * 128 + it16) * 2) * 512 + (size_t)row * 8;
    *(bf16x8*)(dst + base) = hi;          // part 0 (hi)
    *(bf16x8*)(dst + base + 512) = lo;    // part 1 (lo)
  }
}

__global__ __launch_bounds__(256) void k_kq(const float* __restrict__ nodes,
                                            const float* __restrict__ pos,
                                            const float* __restrict__ rot,
                                            const float* __restrict__ w_n,
                                            const float* __restrict__ b_n,
                                            const float* __restrict__ w_p,
                                            const float* __restrict__ b_p,
                                            const float* __restrict__ w_r) {
  const int it16 = blockIdx.x;        // 0..127 -> i base it16*16
  const int oh   = blockIdx.y;        // 0..1   -> o base oh*256
  const int tx = threadIdx.x;
  const int i0 = it16 * 16;

  __shared__ __align__(16) float n_sh[16][128];
  __shared__ float pf_sh[16][8];
  __shared__ float rr_sh[16][4];
  __shared__ unsigned res[256 * 17];  // [o_loc][i], +1 pad

  for (int idx = tx; idx < 512; idx += 256) {
    int r = idx >> 5, c4 = idx & 31;
    *(float4*)&n_sh[r][c4 * 4] = ((const float4*)nodes)[((i0 + r) * 128 >> 2) + c4];
  }
  if (tx < 48) {
    int r = tx / 3, t = tx - r * 3;
    float p = pos[(i0 + r) * 3 + t];
    pf_sh[r][t]     = cosf(6.283185307179586f * p);
    pf_sh[r][t + 3] = sinf(6.283185307179586f * p);
  }
  if (tx >= 64 && tx < 128) {
    int r = (tx - 64) >> 2, t = tx & 3;
    rr_sh[r][t] = rot[(i0 + r) * 4 + t];
  }
  __syncthreads();

  const int og = tx & 63, ig = tx >> 6;   // 4 o x 4 i tile per thread

  // ---- nodes branch (heads 0..7) ----
  {
    float acc[4][4];
    int ob[4];
#pragma unroll
    for (int oo = 0; oo < 4; ++oo) {
      ob[oo] = oh * 256 + oo * 64 + og;
      float bb = b_n[ob[oo]];
#pragma unroll
      for (int ii = 0; ii < 4; ++ii) acc[oo][ii] = bb;
    }
    const float4* wb[4];
#pragma unroll
    for (int oo = 0; oo < 4; ++oo) wb[oo] = (const float4*)(w_n + (size_t)ob[oo] * 128);
    for (int d4 = 0; d4 < 32; ++d4) {
      float4 nv[4];
#pragma unroll
      for (int ii = 0; ii < 4; ++ii) nv[ii] = *(const float4*)&n_sh[ig * 4 + ii][d4 * 4];
#pragma unroll
      for (int oo = 0; oo < 4; ++oo) {
        float4 wv = wb[oo][d4];
#pragma unroll
        for (int ii = 0; ii < 4; ++ii)
          acc[oo][ii] += nv[ii].x * wv.x + nv[ii].y * wv.y + nv[ii].z * wv.z + nv[ii].w * wv.w;
      }
    }
#pragma unroll
    for (int oo = 0; oo < 4; ++oo) {
      float sc = ((ob[oo] & 63) < 32) ? L2E : 1.f;   // scale k only
#pragma unroll
      for (int ii = 0; ii < 4; ++ii) {
        float v = acc[oo][ii] * sc;
        unsigned short hi = f2b(v);
        unsigned short lo = f2b(v - b2f(hi));
        res[(oo * 64 + og) * 17 + ig * 4 + ii] = ((unsigned)hi << 16) | lo;
      }
    }
  }
  __syncthreads();
  repack_store(res, oh, it16, tx, 0);
  __syncthreads();

  // ---- pos branch (heads 8..15) ----
  {
#pragma unroll
    for (int oo = 0; oo < 4; ++oo) {
      int o = oh * 256 + oo * 64 + og;
      float bb = b_p[o];
      float w0 = w_p[o * 6 + 0], w1 = w_p[o * 6 + 1], w2 = w_p[o * 6 + 2];
      float w3 = w_p[o * 6 + 3], w4 = w_p[o * 6 + 4], w5 = w_p[o * 6 + 5];
      float sc = ((o & 63) < 32) ? L2E : 1.f;
#pragma unroll
      for (int ii = 0; ii < 4; ++ii) {
        int i = ig * 4 + ii;
        float v = bb + pf_sh[i][0] * w0 + pf_sh[i][1] * w1 + pf_sh[i][2] * w2
                     + pf_sh[i][3] * w3 + pf_sh[i][4] * w4 + pf_sh[i][5] * w5;
        v *= sc;
        unsigned short hi = f2b(v);
        unsigned short lo = f2b(v - b2f(hi));
        res[(oo * 64 + og) * 17 + i] = ((unsigned)hi << 16) | lo;
      }
    }
  }
  __syncthreads();
  repack_store(res, oh, it16, tx, 8);
  __syncthreads();

  // ---- rot branch (heads 16..23, no bias) ----
  {
#pragma unroll
    for (int oo = 0; oo < 4; ++oo) {
      int o = oh * 256 + oo * 64 + og;
      float w0 = w_r[o * 4 + 0], w1 = w_r[o * 4 + 1], w2 = w_r[o * 4 + 2], w3 = w_r[o * 4 + 3];
      float sc = ((o & 63) < 32) ? SQRT_L2E : 1.f;
#pragma unroll
      for (int ii = 0; ii < 4; ++ii) {
        int i = ig * 4 + ii;
        float v = (rr_sh[i][0] * w0 + rr_sh[i][1] * w1 + rr_sh[i][2] * w2 + rr_sh[i][3] * w3) * sc;
        unsigned short hi = f2b(v);
        unsigned short lo = f2b(v - b2f(hi));
        res[(oo * 64 + og) * 17 + i] = ((unsigned)hi << 16) | lo;
      }
    }
  }
  __syncthreads();
  repack_store(res, oh, it16, tx, 16);
}

// ---------- zero output ----------
__global__ __launch_bounds__(256) void k_zero(float* __restrict__ out) {
  out[blockIdx.x * 256 + threadIdx.x] = 0.f;
}

// ---------- MFMA flash attention, barrier-free waves ----------
// block = (64-i tile, head); wave w owns i-block it*4+w and sweeps all j.
__global__ __launch_bounds__(256) void k_attn(float* __restrict__ out) {
  const int it = blockIdx.x;            // 0..31
  const int g  = blockIdx.y;            // 0..23
  const int tx = threadIdx.x;
  const int w = tx >> 6, lane = tx & 63;
  const int quad = lane >> 4, n = lane & 15;
  const int iblk = it * 4 + w;

  __shared__ __align__(16) unsigned long long p_lds[4][64][2];  // per-wave P A-frags
  __shared__ __align__(16) float bc[4][16];                     // per-wave row broadcast

  // persistent K B-frags (16 i rows, hi/lo)
  const bf16x8* kp = (const bf16x8*)g_kkp + (size_t)(g * 128 + iblk) * 2 * 64;
  const bf16x8 khi = kp[lane], klo = kp[64 + lane];

  f32x4 oacc[8];
#pragma unroll
  for (int db = 0; db < 8; ++db)
#pragma unroll
    for (int r = 0; r < 4; ++r) oacc[db][r] = 0.f;

  float m_run = -3.0e38f, l_run = 0.f;
  const bool is_rot = (g >= 16);
  const int pin = (lane & 56) | ((lane ^ (lane >> 3)) & 7);   // swizzled read row
  const int wrow0 = (quad >> 1) * 16 + n;                     // jb=0 write row
  const int wrow1 = wrow0 + 32;                               // jb=1
  const int pr0 = (wrow0 & 56) | ((wrow0 ^ (wrow0 >> 3)) & 7);
  const int pr1 = (wrow1 & 56) | ((wrow1 ^ (wrow1 >> 3)) & 7);
  const int whalf = quad & 1;

  const bf16x8* qb = (const bf16x8*)g_qqp + (size_t)g * 128 * 2 * 64;
  const bf16x8* vb = (const bf16x8*)g_vvp + (size_t)g * 64 * 8 * 64;

  for (int jt = 0; jt < 64; ++jt) {
    // --- S^T = Q·K^T (A=q: m=j, B=k: n=i); split bf16 hi/lo
    const bf16x8* q0 = qb + (size_t)jt * 256;
    bf16x8 q0h = q0[lane], q0l = q0[64 + lane];
    bf16x8 q1h = q0[128 + lane], q1l = q0[192 + lane];
    f32x4 S0 = {0.f, 0.f, 0.f, 0.f}, S1 = {0.f, 0.f, 0.f, 0.f};
    S0 = __builtin_amdgcn_mfma_f32_16x16x32_bf16(q0h, khi, S0, 0, 0, 0);
    S1 = __builtin_amdgcn_mfma_f32_16x16x32_bf16(q1h, khi, S1, 0, 0, 0);
    S0 = __builtin_amdgcn_mfma_f32_16x16x32_bf16(q0l, khi, S0, 0, 0, 0);
    S1 = __builtin_amdgcn_mfma_f32_16x16x32_bf16(q1l, khi, S1, 0, 0, 0);
    S0 = __builtin_amdgcn_mfma_f32_16x16x32_bf16(q0h, klo, S0, 0, 0, 0);
    S1 = __builtin_amdgcn_mfma_f32_16x16x32_bf16(q1h, klo, S1, 0, 0, 0);
    if (is_rot) {
#pragma unroll
      for (int r = 0; r < 4; ++r) { S0[r] *= S0[r]; S1[r] *= S1[r]; }
    }
    // --- column(i)-max over the 32 j: 8 regs + 2 shuffles
    float mb = fmaxf(fmaxf(fmaxf(S0[0], S0[1]), fmaxf(S0[2], S0[3])),
                     fmaxf(fmaxf(S1[0], S1[1]), fmaxf(S1[2], S1[3])));
    mb = fmaxf(mb, __shfl_xor(mb, 16));
    mb = fmaxf(mb, __shfl_xor(mb, 32));
    if (__ballot(mb > m_run)) {              // wave-uniform; rare after warm-up
      float m_new = fmaxf(m_run, mb);
      float alpha = exp2f(m_run - m_new);
      l_run *= alpha;
      m_run = m_new;
      if (lane < 16) bc[w][lane] = alpha;    // wave-synchronous LDS broadcast
      f32x4 av = *(const f32x4*)&bc[w][quad * 4];
#pragma unroll
      for (int db = 0; db < 8; ++db) {
        oacc[db][0] *= av[0]; oacc[db][1] *= av[1];
        oacc[db][2] *= av[2]; oacc[db][3] *= av[3];
      }
    }
    // --- P = 2^(S - m) (log2e pre-folded into K)
    float p0[4], p1[4];
    float s = 0.f;
#pragma unroll
    for (int r = 0; r < 4; ++r) {
      p0[r] = exp2f(S0[r] - m_run);
      p1[r] = exp2f(S1[r] - m_run);
      s += p0[r] + p1[r];
    }
    s += __shfl_xor(s, 16);
    s += __shfl_xor(s, 32);
    l_run += s;
    // --- stash P as bf16 A-frags (swizzled rows), same-wave LDS round trip
    unsigned long long v0 = ((unsigned long long)pk2(p0[2], p0[3]) << 32) | pk2(p0[0], p0[1]);
    unsigned long long v1 = ((unsigned long long)pk2(p1[2], p1[3]) << 32) | pk2(p1[0], p1[1]);
    p_lds[w][pr0][whalf] = v0;
    p_lds[w][pr1][whalf] = v1;
    bf16x8 a = *(const bf16x8*)&p_lds[w][pin][0];
    // --- PV: O += P x V over this 32-j chunk
    const bf16x8* vp = vb + (size_t)jt * 512;
#pragma unroll
    for (int db = 0; db < 8; ++db) {
      bf16x8 bv = vp[db * 64 + lane];
      oacc[db] = __builtin_amdgcn_mfma_f32_16x16x32_bf16(a, bv, oacc[db], 0, 0, 0);
    }
  }
  // --- epilogue: scale rows by 1/l, accumulate across heads
  float linv = 1.f / l_run;
  if (lane < 16) bc[w][lane] = linv;
  f32x4 lv = *(const f32x4*)&bc[w][quad * 4];
  const int ibase = it * 64 + w * 16 + quad * 4;
#pragma unroll
  for (int db = 0; db < 8; ++db)
#pragma unroll
    for (int r = 0; r < 4; ++r)
      atomicAdd(&out[(size_t)(ibase + r) * VDIM + db * 16 + n], oacc[db][r] * lv[r]);
}

extern "C" void kernel_launch(void* const* d_in, const int* in_sizes, int n_in,
                              void* d_out, int out_size, void* d_ws, size_t ws_size,
                              hipStream_t stream) {
  const float* nodes = (const float*)d_in[0];
  const float* pos   = (const float*)d_in[1];
  const float* rot   = (const float*)d_in[2];
  const float* w_n   = (const float*)d_in[3];
  const float* b_n   = (const float*)d_in[4];
  const float* w_p   = (const float*)d_in[5];
  const float* b_p   = (const float*)d_in[6];
  const float* w_r   = (const float*)d_in[7];
  const float* w_v   = (const float*)d_in[8];
  const float* b_v   = (const float*)d_in[9];
  float* out = (float*)d_out;

  k_zero<<<dim3((SEQ * VDIM) / 256), 256, 0, stream>>>(out);
  k_val<<<dim3(12, 128), 256, 0, stream>>>(nodes, w_v, b_v);
  k_kq<<<dim3(128, 2), 256, 0, stream>>>(nodes, pos, rot, w_n, b_n, w_p, b_p, w_r);
  k_attn<<<dim3(32, NHEAD), 256, 0, stream>>>(out);
}

// Round 6
// 255.260 us; speedup vs baseline: 5.4117x; 1.3631x over previous
//
#include <hip/hip_runtime.h>
#include <hip/hip_bf16.h>
#include <math.h>

#define SEQ 2048
#define NHEAD 24     // 3*H
#define CDIM 32
#define VDIM 128

typedef short bf16x8 __attribute__((ext_vector_type(8)));
typedef float f32x4 __attribute__((ext_vector_type(4)));

#define L2E 1.44269504088896f        // log2(e): folded into K so exp2 == exp
#define SQRT_L2E 1.20112240878645f   // sqrt(log2 e): rot logits get squared

// Frag-packed operand buffers (bf16 as ushort).
// K B-frags + Q A-frags, hi/lo split: [g][blk16(128)][part(2)][lane(64)][e(8)]
__device__ unsigned short g_kkp[(size_t)24 * 128 * 2 * 64 * 8];
__device__ unsigned short g_qqp[(size_t)24 * 128 * 2 * 64 * 8];
// V B-frags: [g][jb32(64)][db16(8)][lane(64)][e(8)]
__device__ unsigned short g_vvp[(size_t)24 * 64 * 8 * 64 * 8];

__device__ __forceinline__ unsigned short f2b(float x) {   // RNE f32->bf16
  union { float f; unsigned u; } v; v.f = x;
  unsigned r = v.u + 0x7FFF + ((v.u >> 16) & 1);
  return (unsigned short)(r >> 16);
}
__device__ __forceinline__ float b2f(unsigned short u) {
  union { unsigned u32; float f; } x; x.u32 = ((unsigned)u) << 16; return x.f;
}
__device__ __forceinline__ unsigned pk2(float a, float b) {  // [lo=a, hi=b] bf16 pair
  __hip_bfloat162 t = __float22bfloat162_rn(float2{a, b});
  union { __hip_bfloat162 h; unsigned u; } c; c.h = t; return c.u;
}
// async global->LDS, 16B per lane; lds dest is wave-uniform base (+lane*16 implicit)
__device__ __forceinline__ void gld16(const unsigned short* g, unsigned short* l) {
  __builtin_amdgcn_global_load_lds(
      (const __attribute__((address_space(1))) unsigned int*)g,
      (__attribute__((address_space(3))) unsigned int*)l, 16, 0, 0);
}

// ---------- values projection -> V B-frags (validated round 4/5) ----------
__global__ __launch_bounds__(256) void k_val(const float* __restrict__ nodes,
                                             const float* __restrict__ w,
                                             const float* __restrict__ b) {
  __shared__ __align__(16) float n_sh[16][128];
  const int tx = threadIdx.x;
  const int o  = blockIdx.x * 256 + tx;     // output column 0..3071
  const int i0 = blockIdx.y * 16;           // row tile (16 consecutive j)
  for (int idx = tx; idx < 16 * 128 / 4; idx += 256) {
    int r = idx >> 5, c4 = idx & 31;
    *(float4*)&n_sh[r][c4 * 4] = ((const float4*)nodes)[((i0 + r) * 128 >> 2) + c4];
  }
  __syncthreads();
  float acc[16];
  const float bias = b[o];
#pragma unroll
  for (int r = 0; r < 16; ++r) acc[r] = bias;
  const float4* w4 = (const float4*)(w + (size_t)o * 128);
  for (int d4 = 0; d4 < 32; ++d4) {
    float4 wv = w4[d4];
#pragma unroll
    for (int r = 0; r < 16; ++r) {
      float4 nv = *(const float4*)&n_sh[r][d4 * 4];
      acc[r] += nv.x * wv.x + nv.y * wv.y + nv.z * wv.z + nv.w * wv.w;
    }
  }
  const int g  = o >> 7, d = o & 127;
  const int jb = i0 >> 5;
  const int db = d >> 4, nn = d & 15;
  const int khb = (i0 & 31) >> 3;         // 0 or 2
#pragma unroll
  for (int half = 0; half < 2; ++half) {
    bf16x8 pk;
#pragma unroll
    for (int e = 0; e < 8; ++e) pk[e] = (short)f2b(acc[half * 8 + e]);
    ((bf16x8*)g_vvp)[((size_t)(g * 64 + jb) * 8 + db) * 64 + (khb + half) * 16 + nn] = pk;
  }
}

// ---------- k/q projections (validated round 5) ----------
__device__ __forceinline__ void repack_store(const unsigned* __restrict__ res,
                                             int oh, int it16, int tx, int head_base) {
#pragma unroll
  for (int t2 = 0; t2 < 2; ++t2) {
    int cid = tx + t2 * 256;           // 0..511
    int hl  = cid >> 7;                // local head 0..3
    int kq  = (cid >> 6) & 1;          // 0=k 1=q
    int row = cid & 63;                // frag lane
    int m = row & 15, kb = row >> 4;
    int ob = hl * 64 + kq * 32 + kb * 8;
    bf16x8 hi, lo;
#pragma unroll
    for (int e = 0; e < 8; ++e) {
      unsigned pk = res[(ob + e) * 17 + m];
      hi[e] = (short)(pk >> 16);
      lo[e] = (short)(pk & 0xffff);
    }
    unsigned short* dst = kq ? g_qqp : g_kkp;
    size_t base = ((size_t)((head_base + oh * 4 + hl) * 128 + it16) * 2) * 512 + (size_t)row * 8;
    *(bf16x8*)(dst + base) = hi;          // part 0 (hi)
    *(bf16x8*)(dst + base + 512) = lo;    // part 1 (lo)
  }
}

__global__ __launch_bounds__(256) void k_kq(const float* __restrict__ nodes,
                                            const float* __restrict__ pos,
                                            const float* __restrict__ rot,
                                            const float* __restrict__ w_n,
                                            const float* __restrict__ b_n,
                                            const float* __restrict__ w_p,
                                            const float* __restrict__ b_p,
                                            const float* __restrict__ w_r) {
  const int it16 = blockIdx.x;        // 0..127 -> i base it16*16
  const int oh   = blockIdx.y;        // 0..1   -> o base oh*256
  const int tx = threadIdx.x;
  const int i0 = it16 * 16;

  __shared__ __align__(16) float n_sh[16][128];
  __shared__ float pf_sh[16][8];
  __shared__ float rr_sh[16][4];
  __shared__ unsigned res[256 * 17];  // [o_loc][i], +1 pad

  for (int idx = tx; idx < 512; idx += 256) {
    int r = idx >> 5, c4 = idx & 31;
    *(float4*)&n_sh[r][c4 * 4] = ((const float4*)nodes)[((i0 + r) * 128 >> 2) + c4];
  }
  if (tx < 48) {
    int r = tx / 3, t = tx - r * 3;
    float p = pos[(i0 + r) * 3 + t];
    pf_sh[r][t]     = cosf(6.283185307179586f * p);
    pf_sh[r][t + 3] = sinf(6.283185307179586f * p);
  }
  if (tx >= 64 && tx < 128) {
    int r = (tx - 64) >> 2, t = tx & 3;
    rr_sh[r][t] = rot[(i0 + r) * 4 + t];
  }
  __syncthreads();

  const int og = tx & 63, ig = tx >> 6;   // 4 o x 4 i tile per thread

  // ---- nodes branch (heads 0..7) ----
  {
    float acc[4][4];
    int ob[4];
#pragma unroll
    for (int oo = 0; oo < 4; ++oo) {
      ob[oo] = oh * 256 + oo * 64 + og;
      float bb = b_n[ob[oo]];
#pragma unroll
      for (int ii = 0; ii < 4; ++ii) acc[oo][ii] = bb;
    }
    const float4* wb[4];
#pragma unroll
    for (int oo = 0; oo < 4; ++oo) wb[oo] = (const float4*)(w_n + (size_t)ob[oo] * 128);
    for (int d4 = 0; d4 < 32; ++d4) {
      float4 nv[4];
#pragma unroll
      for (int ii = 0; ii < 4; ++ii) nv[ii] = *(const float4*)&n_sh[ig * 4 + ii][d4 * 4];
#pragma unroll
      for (int oo = 0; oo < 4; ++oo) {
        float4 wv = wb[oo][d4];
#pragma unroll
        for (int ii = 0; ii < 4; ++ii)
          acc[oo][ii] += nv[ii].x * wv.x + nv[ii].y * wv.y + nv[ii].z * wv.z + nv[ii].w * wv.w;
      }
    }
#pragma unroll
    for (int oo = 0; oo < 4; ++oo) {
      float sc = ((ob[oo] & 63) < 32) ? L2E : 1.f;   // scale k only
#pragma unroll
      for (int ii = 0; ii < 4; ++ii) {
        float v = acc[oo][ii] * sc;
        unsigned short hi = f2b(v);
        unsigned short lo = f2b(v - b2f(hi));
        res[(oo * 64 + og) * 17 + ig * 4 + ii] = ((unsigned)hi << 16) | lo;
      }
    }
  }
  __syncthreads();
  repack_store(res, oh, it16, tx, 0);
  __syncthreads();

  // ---- pos branch (heads 8..15) ----
  {
#pragma unroll
    for (int oo = 0; oo < 4; ++oo) {
      int o = oh * 256 + oo * 64 + og;
      float bb = b_p[o];
      float w0 = w_p[o * 6 + 0], w1 = w_p[o * 6 + 1], w2 = w_p[o * 6 + 2];
      float w3 = w_p[o * 6 + 3], w4 = w_p[o * 6 + 4], w5 = w_p[o * 6 + 5];
      float sc = ((o & 63) < 32) ? L2E : 1.f;
#pragma unroll
      for (int ii = 0; ii < 4; ++ii) {
        int i = ig * 4 + ii;
        float v = bb + pf_sh[i][0] * w0 + pf_sh[i][1] * w1 + pf_sh[i][2] * w2
                     + pf_sh[i][3] * w3 + pf_sh[i][4] * w4 + pf_sh[i][5] * w5;
        v *= sc;
        unsigned short hi = f2b(v);
        unsigned short lo = f2b(v - b2f(hi));
        res[(oo * 64 + og) * 17 + i] = ((unsigned)hi << 16) | lo;
      }
    }
  }
  __syncthreads();
  repack_store(res, oh, it16, tx, 8);
  __syncthreads();

  // ---- rot branch (heads 16..23, no bias) ----
  {
#pragma unroll
    for (int oo = 0; oo < 4; ++oo) {
      int o = oh * 256 + oo * 64 + og;
      float w0 = w_r[o * 4 + 0], w1 = w_r[o * 4 + 1], w2 = w_r[o * 4 + 2], w3 = w_r[o * 4 + 3];
      float sc = ((o & 63) < 32) ? SQRT_L2E : 1.f;
#pragma unroll
      for (int ii = 0; ii < 4; ++ii) {
        int i = ig * 4 + ii;
        float v = (rr_sh[i][0] * w0 + rr_sh[i][1] * w1 + rr_sh[i][2] * w2 + rr_sh[i][3] * w3) * sc;
        unsigned short hi = f2b(v);
        unsigned short lo = f2b(v - b2f(hi));
        res[(oo * 64 + og) * 17 + i] = ((unsigned)hi << 16) | lo;
      }
    }
  }
  __syncthreads();
  repack_store(res, oh, it16, tx, 16);
}

// ---------- zero output ----------
__global__ __launch_bounds__(256) void k_zero(float* __restrict__ out) {
  out[blockIdx.x * 256 + threadIdx.x] = 0.f;
}

// ---------- MFMA flash attention: LDS-shared Q/V, async double-buffer ----------
// block = (64-i tile, head); wave w owns i-block it*4+w; Q/V staged once per block.
__global__ __launch_bounds__(256) void k_attn(float* __restrict__ out) {
  const int it = blockIdx.x;            // 0..31
  const int g  = blockIdx.y;            // 0..23
  const int tx = threadIdx.x;
  const int w = tx >> 6, lane = tx & 63;
  const int quad = lane >> 4, n = lane & 15;
  const int iblk = it * 4 + w;

  // 12 x 1KB frags per j-iter: [0..3]=Q (blk0 hi, blk0 lo, blk1 hi, blk1 lo), [4..11]=V db0..7
  __shared__ __align__(16) unsigned short stage[2][12][64][8];
  __shared__ __align__(16) unsigned long long p_lds[4][64][2];  // per-wave P A-frags
  __shared__ __align__(16) float bc[4][16];                     // per-wave row broadcast

  // persistent K B-frags (16 i rows, hi/lo)
  const bf16x8* kp = (const bf16x8*)g_kkp + (size_t)(g * 128 + iblk) * 2 * 64;
  const bf16x8 khi = kp[lane], klo = kp[64 + lane];

  f32x4 oacc[8];
#pragma unroll
  for (int db = 0; db < 8; ++db)
#pragma unroll
    for (int r = 0; r < 4; ++r) oacc[db][r] = 0.f;

  float m_run = -3.0e38f, l_run = 0.f;
  const bool is_rot = (g >= 16);
  const int pin = (lane & 56) | ((lane ^ (lane >> 3)) & 7);   // swizzled read row
  const int wrow0 = (quad >> 1) * 16 + n;                     // jb=0 write row
  const int wrow1 = wrow0 + 32;                               // jb=1
  const int pr0 = (wrow0 & 56) | ((wrow0 ^ (wrow0 >> 3)) & 7);
  const int pr1 = (wrow1 & 56) | ((wrow1 ^ (wrow1 >> 3)) & 7);
  const int whalf = quad & 1;

  const unsigned short* qsrc = g_qqp + (size_t)g * 128 * 2 * 512;  // frag = 512 ushorts
  const unsigned short* vsrc = g_vvp + (size_t)g * 64 * 8 * 512;
  const unsigned short* gsrc0 = qsrc - 4 * 512;   // so frag f>=4 maps into vsrc cleanly below

  // stage frags for iteration jt into buffer nb: wave w handles frags 3w..3w+2
#define STAGE(nb, jt)                                                          \
  {                                                                            \
    const int f0_ = w * 3;                                                     \
    _Pragma("unroll")                                                          \
    for (int s_ = 0; s_ < 3; ++s_) {                                           \
      int f_ = f0_ + s_;                                                       \
      const unsigned short* gp_ = (f_ < 4)                                     \
          ? qsrc + (((size_t)(jt) * 4 + f_) << 9)                              \
          : vsrc + (((size_t)(jt) * 8 + (f_ - 4)) << 9);                       \
      gld16(gp_ + lane * 8, &stage[nb][f_][0][0]);                             \
    }                                                                          \
  }

  STAGE(0, 0);

  for (int jt = 0; jt < 64; ++jt) {
    const int buf = jt & 1;
    __syncthreads();                  // own vmcnt drained by compiler -> stage[buf] ready
    if (jt < 63) STAGE(buf ^ 1, jt + 1);   // async prefetch overlaps compute below

    const bf16x8* st = (const bf16x8*)&stage[buf][0][0][0];
    // --- S^T = Q·K^T (A=q: m=j, B=k: n=i); split bf16 hi/lo
    bf16x8 q0h = st[lane], q0l = st[64 + lane];
    bf16x8 q1h = st[128 + lane], q1l = st[192 + lane];
    f32x4 S0 = {0.f, 0.f, 0.f, 0.f}, S1 = {0.f, 0.f, 0.f, 0.f};
    S0 = __builtin_amdgcn_mfma_f32_16x16x32_bf16(q0h, khi, S0, 0, 0, 0);
    S1 = __builtin_amdgcn_mfma_f32_16x16x32_bf16(q1h, khi, S1, 0, 0, 0);
    S0 = __builtin_amdgcn_mfma_f32_16x16x32_bf16(q0l, khi, S0, 0, 0, 0);
    S1 = __builtin_amdgcn_mfma_f32_16x16x32_bf16(q1l, khi, S1, 0, 0, 0);
    S0 = __builtin_amdgcn_mfma_f32_16x16x32_bf16(q0h, klo, S0, 0, 0, 0);
    S1 = __builtin_amdgcn_mfma_f32_16x16x32_bf16(q1h, klo, S1, 0, 0, 0);
    if (is_rot) {
#pragma unroll
      for (int r = 0; r < 4; ++r) { S0[r] *= S0[r]; S1[r] *= S1[r]; }
    }
    // --- column(i)-max over the 32 j
    float mb = fmaxf(fmaxf(fmaxf(S0[0], S0[1]), fmaxf(S0[2], S0[3])),
                     fmaxf(fmaxf(S1[0], S1[1]), fmaxf(S1[2], S1[3])));
    mb = fmaxf(mb, __shfl_xor(mb, 16));
    mb = fmaxf(mb, __shfl_xor(mb, 32));
    if (__ballot(mb > m_run)) {              // wave-uniform
      float m_new = fmaxf(m_run, mb);
      float alpha = exp2f(m_run - m_new);
      l_run *= alpha;
      m_run = m_new;
      if (lane < 16) bc[w][lane] = alpha;    // wave-synchronous LDS broadcast
      f32x4 av = *(const f32x4*)&bc[w][quad * 4];
#pragma unroll
      for (int db = 0; db < 8; ++db) {
        oacc[db][0] *= av[0]; oacc[db][1] *= av[1];
        oacc[db][2] *= av[2]; oacc[db][3] *= av[3];
      }
    }
    // --- P = 2^(S - m) (log2e pre-folded into K)
    float p0[4], p1[4];
    float s = 0.f;
#pragma unroll
    for (int r = 0; r < 4; ++r) {
      p0[r] = exp2f(S0[r] - m_run);
      p1[r] = exp2f(S1[r] - m_run);
      s += p0[r] + p1[r];
    }
    s += __shfl_xor(s, 16);
    s += __shfl_xor(s, 32);
    l_run += s;
    // --- stash P as bf16 A-frags (swizzled rows), same-wave LDS round trip
    unsigned long long v0 = ((unsigned long long)pk2(p0[2], p0[3]) << 32) | pk2(p0[0], p0[1]);
    unsigned long long v1 = ((unsigned long long)pk2(p1[2], p1[3]) << 32) | pk2(p1[0], p1[1]);
    p_lds[w][pr0][whalf] = v0;
    p_lds[w][pr1][whalf] = v1;
    bf16x8 a = *(const bf16x8*)&p_lds[w][pin][0];
    // --- PV: O += P x V over this 32-j chunk (V from LDS)
#pragma unroll
    for (int db = 0; db < 8; ++db) {
      bf16x8 bv = st[(4 + db) * 64 + lane];
      oacc[db] = __builtin_amdgcn_mfma_f32_16x16x32_bf16(a, bv, oacc[db], 0, 0, 0);
    }
  }
  (void)gsrc0;
  // --- epilogue: scale rows by 1/l, accumulate across heads
  float linv = 1.f / l_run;
  if (lane < 16) bc[w][lane] = linv;
  f32x4 lv = *(const f32x4*)&bc[w][quad * 4];
  const int ibase = it * 64 + w * 16 + quad * 4;
#pragma unroll
  for (int db = 0; db < 8; ++db)
#pragma unroll
    for (int r = 0; r < 4; ++r)
      atomicAdd(&out[(size_t)(ibase + r) * VDIM + db * 16 + n], oacc[db][r] * lv[r]);
}

extern "C" void kernel_launch(void* const* d_in, const int* in_sizes, int n_in,
                              void* d_out, int out_size, void* d_ws, size_t ws_size,
                              hipStream_t stream) {
  const float* nodes = (const float*)d_in[0];
  const float* pos   = (const float*)d_in[1];
  const float* rot   = (const float*)d_in[2];
  const float* w_n   = (const float*)d_in[3];
  const float* b_n   = (const float*)d_in[4];
  const float* w_p   = (const float*)d_in[5];
  const float* b_p   = (const float*)d_in[6];
  const float* w_r   = (const float*)d_in[7];
  const float* w_v   = (const float*)d_in[8];
  const float* b_v   = (const float*)d_in[9];
  float* out = (float*)d_out;

  k_zero<<<dim3((SEQ * VDIM) / 256), 256, 0, stream>>>(out);
  k_val<<<dim3(12, 128), 256, 0, stream>>>(nodes, w_v, b_v);
  k_kq<<<dim3(128, 2), 256, 0, stream>>>(nodes, pos, rot, w_n, b_n, w_p, b_p, w_r);
  k_attn<<<dim3(32, NHEAD), 256, 0, stream>>>(out);
}

// Round 8
// 220.476 us; speedup vs baseline: 6.2655x; 1.1578x over previous
//
#include <hip/hip_runtime.h>
#include <hip/hip_bf16.h>
#include <math.h>

#define SEQ 2048
#define NHEAD 24     // 3*H
#define CDIM 32
#define VDIM 128

typedef short bf16x8 __attribute__((ext_vector_type(8)));
typedef float f32x4 __attribute__((ext_vector_type(4)));

#define L2E 1.44269504088896f        // log2(e): folded into K so exp2 == exp
#define SQRT_L2E 1.20112240878645f   // sqrt(log2 e): rot logits get squared

#if __has_builtin(__builtin_amdgcn_exp2f)
#define EXP2(x) __builtin_amdgcn_exp2f(x)
#else
#define EXP2(x) exp2f(x)
#endif

// K B-frags, hi/lo split: [g][blk16(128)][part(2)][lane(64)][e(8)]
__device__ unsigned short g_kkp[(size_t)24 * 128 * 2 * 64 * 8];
// Interleaved Q+V staging source: [g][jt(32 x 64j)][frag(24)][lane(64)][e(8)]
//   frag 0..7  = Q A-frags: [jb(4)][hi/lo]
//   frag 8..23 = V B-frags: [jchunk(2)][db(8)]
__device__ unsigned short g_qv[(size_t)24 * 32 * 24 * 64 * 8];

__device__ __forceinline__ unsigned short f2b(float x) {   // RNE f32->bf16
  union { float f; unsigned u; } v; v.f = x;
  unsigned r = v.u + 0x7FFF + ((v.u >> 16) & 1);
  return (unsigned short)(r >> 16);
}
__device__ __forceinline__ float b2f(unsigned short u) {
  union { unsigned u32; float f; } x; x.u32 = ((unsigned)u) << 16; return x.f;
}
__device__ __forceinline__ unsigned pk2(float a, float b) {  // [lo=a, hi=b] bf16 pair
  __hip_bfloat162 t = __float22bfloat162_rn(float2{a, b});
  union { __hip_bfloat162 h; unsigned u; } c; c.h = t; return c.u;
}
__device__ __forceinline__ unsigned long long pack64(const float* p) {
  return ((unsigned long long)pk2(p[2], p[3]) << 32) | pk2(p[0], p[1]);
}
// async global->LDS, 16B/lane; offset folded into pointer (imm must be ICE -> 0)
__device__ __forceinline__ void gld16(const unsigned short* g, unsigned short* l) {
  __builtin_amdgcn_global_load_lds(
      (const __attribute__((address_space(1))) unsigned int*)g,
      (__attribute__((address_space(3))) unsigned int*)l, 16, 0, 0);
}

// ---------- values projection -> V B-frag slots of g_qv ----------
__global__ __launch_bounds__(256) void k_val(const float* __restrict__ nodes,
                                             const float* __restrict__ w,
                                             const float* __restrict__ b) {
  __shared__ __align__(16) float n_sh[16][128];
  const int tx = threadIdx.x;
  const int o  = blockIdx.x * 256 + tx;     // output column 0..3071
  const int i0 = blockIdx.y * 16;           // j-row tile
  for (int idx = tx; idx < 16 * 128 / 4; idx += 256) {
    int r = idx >> 5, c4 = idx & 31;
    *(float4*)&n_sh[r][c4 * 4] = ((const float4*)nodes)[((i0 + r) * 128 >> 2) + c4];
  }
  __syncthreads();
  float acc[16];
  const float bias = b[o];
#pragma unroll
  for (int r = 0; r < 16; ++r) acc[r] = bias;
  const float4* w4 = (const float4*)(w + (size_t)o * 128);
  for (int d4 = 0; d4 < 32; ++d4) {
    float4 wv = w4[d4];
#pragma unroll
    for (int r = 0; r < 16; ++r) {
      float4 nv = *(const float4*)&n_sh[r][d4 * 4];
      acc[r] += nv.x * wv.x + nv.y * wv.y + nv.z * wv.z + nv.w * wv.w;
    }
  }
  const int g  = o >> 7, d = o & 127;
  const int jt = i0 >> 6;                 // 64-j tile
  const int jc = (i0 >> 5) & 1;           // 32-j chunk
  const int db = d >> 4, nn = d & 15;
  const int khb = (i0 & 31) >> 3;         // 0 or 2
#pragma unroll
  for (int half = 0; half < 2; ++half) {
    bf16x8 pk;
#pragma unroll
    for (int e = 0; e < 8; ++e) pk[e] = (short)f2b(acc[half * 8 + e]);
    ((bf16x8*)g_qv)[(((size_t)g * 32 + jt) * 24 + 8 + jc * 8 + db) * 64 + (khb + half) * 16 + nn] = pk;
  }
}

// ---------- k/q repack: K -> g_kkp, Q -> g_qv frag slots ----------
__device__ __forceinline__ void repack_store(const unsigned* __restrict__ res,
                                             int oh, int it16, int tx, int head_base) {
#pragma unroll
  for (int t2 = 0; t2 < 2; ++t2) {
    int cid = tx + t2 * 256;           // 0..511
    int hl  = cid >> 7;                // local head 0..3
    int kq  = (cid >> 6) & 1;          // 0=k 1=q
    int row = cid & 63;                // frag lane
    int m = row & 15, kb = row >> 4;
    int ob = hl * 64 + kq * 32 + kb * 8;
    bf16x8 hi, lo;
#pragma unroll
    for (int e = 0; e < 8; ++e) {
      unsigned pk = res[(ob + e) * 17 + m];
      hi[e] = (short)(pk >> 16);
      lo[e] = (short)(pk & 0xffff);
    }
    int gh = head_base + oh * 4 + hl;
    if (kq == 0) {
      size_t base = ((size_t)(gh * 128 + it16) * 2) * 512 + (size_t)row * 8;
      *(bf16x8*)(g_kkp + base) = hi;
      *(bf16x8*)(g_kkp + base + 512) = lo;
    } else {
      int jt = it16 >> 2, jb = it16 & 3;
      size_t base = (((size_t)gh * 32 + jt) * 24 + jb * 2) * 512 + (size_t)row * 8;
      *(bf16x8*)(g_qv + base) = hi;
      *(bf16x8*)(g_qv + base + 512) = lo;
    }
  }
}

// grid (128, 2, 3): z = branch (0 nodes, 1 pos, 2 rot)
__global__ __launch_bounds__(256) void k_kq(const float* __restrict__ nodes,
                                            const float* __restrict__ pos,
                                            const float* __restrict__ rot,
                                            const float* __restrict__ w_n,
                                            const float* __restrict__ b_n,
                                            const float* __restrict__ w_p,
                                            const float* __restrict__ b_p,
                                            const float* __restrict__ w_r) {
  const int it16 = blockIdx.x;        // 0..127 -> i base it16*16
  const int oh   = blockIdx.y;        // 0..1   -> o base oh*256
  const int br   = blockIdx.z;        // branch
  const int tx = threadIdx.x;
  const int i0 = it16 * 16;

  __shared__ __align__(16) float n_sh[16][128];
  __shared__ float pf_sh[16][8];
  __shared__ float rr_sh[16][4];
  __shared__ unsigned res[256 * 17];  // [o_loc][i], +1 pad

  if (br == 0) {
    for (int idx = tx; idx < 512; idx += 256) {
      int r = idx >> 5, c4 = idx & 31;
      *(float4*)&n_sh[r][c4 * 4] = ((const float4*)nodes)[((i0 + r) * 128 >> 2) + c4];
    }
  } else if (br == 1) {
    if (tx < 48) {
      int r = tx / 3, t = tx - r * 3;
      float p = pos[(i0 + r) * 3 + t];
      pf_sh[r][t]     = cosf(6.283185307179586f * p);
      pf_sh[r][t + 3] = sinf(6.283185307179586f * p);
    }
  } else {
    if (tx < 64) {
      int r = tx >> 2, t = tx & 3;
      rr_sh[r][t] = rot[(i0 + r) * 4 + t];
    }
  }
  __syncthreads();

  const int og = tx & 63, ig = tx >> 6;   // 4 o x 4 i tile per thread

  if (br == 0) {
    float acc[4][4];
    int ob[4];
#pragma unroll
    for (int oo = 0; oo < 4; ++oo) {
      ob[oo] = oh * 256 + oo * 64 + og;
      float bb = b_n[ob[oo]];
#pragma unroll
      for (int ii = 0; ii < 4; ++ii) acc[oo][ii] = bb;
    }
    const float4* wb[4];
#pragma unroll
    for (int oo = 0; oo < 4; ++oo) wb[oo] = (const float4*)(w_n + (size_t)ob[oo] * 128);
    for (int d4 = 0; d4 < 32; ++d4) {
      float4 nv[4];
#pragma unroll
      for (int ii = 0; ii < 4; ++ii) nv[ii] = *(const float4*)&n_sh[ig * 4 + ii][d4 * 4];
#pragma unroll
      for (int oo = 0; oo < 4; ++oo) {
        float4 wv = wb[oo][d4];
#pragma unroll
        for (int ii = 0; ii < 4; ++ii)
          acc[oo][ii] += nv[ii].x * wv.x + nv[ii].y * wv.y + nv[ii].z * wv.z + nv[ii].w * wv.w;
      }
    }
#pragma unroll
    for (int oo = 0; oo < 4; ++oo) {
      float sc = ((ob[oo] & 63) < 32) ? L2E : 1.f;
#pragma unroll
      for (int ii = 0; ii < 4; ++ii) {
        float v = acc[oo][ii] * sc;
        unsigned short hi = f2b(v);
        unsigned short lo = f2b(v - b2f(hi));
        res[(oo * 64 + og) * 17 + ig * 4 + ii] = ((unsigned)hi << 16) | lo;
      }
    }
  } else if (br == 1) {
#pragma unroll
    for (int oo = 0; oo < 4; ++oo) {
      int o = oh * 256 + oo * 64 + og;
      float bb = b_p[o];
      float w0 = w_p[o * 6 + 0], w1 = w_p[o * 6 + 1], w2 = w_p[o * 6 + 2];
      float w3 = w_p[o * 6 + 3], w4 = w_p[o * 6 + 4], w5 = w_p[o * 6 + 5];
      float sc = ((o & 63) < 32) ? L2E : 1.f;
#pragma unroll
      for (int ii = 0; ii < 4; ++ii) {
        int i = ig * 4 + ii;
        float v = bb + pf_sh[i][0] * w0 + pf_sh[i][1] * w1 + pf_sh[i][2] * w2
                     + pf_sh[i][3] * w3 + pf_sh[i][4] * w4 + pf_sh[i][5] * w5;
        v *= sc;
        unsigned short hi = f2b(v);
        unsigned short lo = f2b(v - b2f(hi));
        res[(oo * 64 + og) * 17 + i] = ((unsigned)hi << 16) | lo;
      }
    }
  } else {
#pragma unroll
    for (int oo = 0; oo < 4; ++oo) {
      int o = oh * 256 + oo * 64 + og;
      float w0 = w_r[o * 4 + 0], w1 = w_r[o * 4 + 1], w2 = w_r[o * 4 + 2], w3 = w_r[o * 4 + 3];
      float sc = ((o & 63) < 32) ? SQRT_L2E : 1.f;
#pragma unroll
      for (int ii = 0; ii < 4; ++ii) {
        int i = ig * 4 + ii;
        float v = (rr_sh[i][0] * w0 + rr_sh[i][1] * w1 + rr_sh[i][2] * w2 + rr_sh[i][3] * w3) * sc;
        unsigned short hi = f2b(v);
        unsigned short lo = f2b(v - b2f(hi));
        res[(oo * 64 + og) * 17 + i] = ((unsigned)hi << 16) | lo;
      }
    }
  }
  __syncthreads();
  repack_store(res, oh, it16, tx, br * 8);
}

// ---------- zero output ----------
__global__ __launch_bounds__(256) void k_zero(float* __restrict__ out) {
  out[blockIdx.x * 256 + threadIdx.x] = 0.f;
}

// ---------- MFMA flash attention: 64 j per iter, LDS-staged Q+V ----------
__global__ __launch_bounds__(256) void k_attn(float* __restrict__ out) {
  const int it = blockIdx.x;            // 0..31
  const int g  = blockIdx.y;            // 0..23
  const int tx = threadIdx.x;
  const int w = tx >> 6, lane = tx & 63;
  const int quad = lane >> 4, n = lane & 15;
  const int iblk = it * 4 + w;

  __shared__ __align__(16) unsigned short stage[2][24][64][8];   // 48 KB
  __shared__ __align__(16) unsigned long long p_lds[4][64][2];   // 4 KB, reused per chunk
  __shared__ __align__(16) float bc[4][16];

  // persistent K B-frags (16 i rows, hi/lo)
  const bf16x8* kp = (const bf16x8*)g_kkp + (size_t)(g * 128 + iblk) * 2 * 64;
  const bf16x8 khi = kp[lane], klo = kp[64 + lane];

  f32x4 oacc[8];
#pragma unroll
  for (int db = 0; db < 8; ++db)
#pragma unroll
    for (int r = 0; r < 4; ++r) oacc[db][r] = 0.f;

  float m_run = -3.0e38f, l_run = 0.f;
  const bool is_rot = (g >= 16);
  const int pin = (lane & 56) | ((lane ^ (lane >> 3)) & 7);   // swizzled read row
  const int wrow0 = (quad >> 1) * 16 + n;
  const int wrow1 = wrow0 + 32;
  const int pr0 = (wrow0 & 56) | ((wrow0 ^ (wrow0 >> 3)) & 7);
  const int pr1 = (wrow1 & 56) | ((wrow1 ^ (wrow1 >> 3)) & 7);
  const int whalf = quad & 1;

  const unsigned short* qv = g_qv + ((size_t)g * 32 * 24 + w * 6) * 512 + (size_t)lane * 8;

#define STG(nb)                                          \
  { gld16(qv,             &stage[nb][w * 6 + 0][0][0]);  \
    gld16(qv + 512,       &stage[nb][w * 6 + 1][0][0]);  \
    gld16(qv + 1024,      &stage[nb][w * 6 + 2][0][0]);  \
    gld16(qv + 1536,      &stage[nb][w * 6 + 3][0][0]);  \
    gld16(qv + 2048,      &stage[nb][w * 6 + 4][0][0]);  \
    gld16(qv + 2560,      &stage[nb][w * 6 + 5][0][0]); }

  STG(0)

  for (int jt = 0; jt < 32; ++jt) {
    const int buf = jt & 1;
    __syncthreads();                       // stage[buf] ready (vmcnt drained)
    qv += 24 * 512;
    if (jt < 31) STG(buf ^ 1)              // async prefetch overlaps compute

    const bf16x8* st = (const bf16x8*)&stage[buf][0][0][0];
    // --- S^T = Q·K^T for 4 j-blocks (A=q m=j, B=k n=i), split bf16 hi/lo
    f32x4 S[4];
#pragma unroll
    for (int jb = 0; jb < 4; ++jb) {
      bf16x8 qh = st[(jb * 2) * 64 + lane], ql = st[(jb * 2 + 1) * 64 + lane];
      f32x4 a = {0.f, 0.f, 0.f, 0.f};
      a = __builtin_amdgcn_mfma_f32_16x16x32_bf16(qh, khi, a, 0, 0, 0);
      a = __builtin_amdgcn_mfma_f32_16x16x32_bf16(ql, khi, a, 0, 0, 0);
      a = __builtin_amdgcn_mfma_f32_16x16x32_bf16(qh, klo, a, 0, 0, 0);
      S[jb] = a;
    }
    if (is_rot) {
#pragma unroll
      for (int jb = 0; jb < 4; ++jb)
#pragma unroll
        for (int r = 0; r < 4; ++r) S[jb][r] *= S[jb][r];
    }
    // --- column(i)-max over 64 j
    float mb = S[0][0];
#pragma unroll
    for (int jb = 0; jb < 4; ++jb)
#pragma unroll
      for (int r = 0; r < 4; ++r) mb = fmaxf(mb, S[jb][r]);
    mb = fmaxf(mb, __shfl_xor(mb, 16));
    mb = fmaxf(mb, __shfl_xor(mb, 32));
    if (__ballot(mb > m_run)) {            // wave-uniform
      float m_new = fmaxf(m_run, mb);
      float alpha = EXP2(m_run - m_new);
      l_run *= alpha;
      m_run = m_new;
      if (lane < 16) bc[w][lane] = alpha;
      f32x4 av = *(const f32x4*)&bc[w][quad * 4];
#pragma unroll
      for (int db = 0; db < 8; ++db) {
        oacc[db][0] *= av[0]; oacc[db][1] *= av[1];
        oacc[db][2] *= av[2]; oacc[db][3] *= av[3];
      }
    }
    // --- P = 2^(S - m); sum
    float p[4][4];
    float s = 0.f;
#pragma unroll
    for (int jb = 0; jb < 4; ++jb)
#pragma unroll
      for (int r = 0; r < 4; ++r) {
        p[jb][r] = EXP2(S[jb][r] - m_run);
        s += p[jb][r];
      }
    s += __shfl_xor(s, 16);
    s += __shfl_xor(s, 32);
    l_run += s;
    // --- PV chunk 0 (j 0..31): P round-trip + 8 MFMA
    p_lds[w][pr0][whalf] = pack64(p[0]);
    p_lds[w][pr1][whalf] = pack64(p[1]);
    bf16x8 a0 = *(const bf16x8*)&p_lds[w][pin][0];
#pragma unroll
    for (int db = 0; db < 8; ++db)
      oacc[db] = __builtin_amdgcn_mfma_f32_16x16x32_bf16(a0, st[(8 + db) * 64 + lane], oacc[db], 0, 0, 0);
    // --- PV chunk 1 (j 32..63): reuse p_lds (wave-local, in-order DS)
    p_lds[w][pr0][whalf] = pack64(p[2]);
    p_lds[w][pr1][whalf] = pack64(p[3]);
    bf16x8 a1 = *(const bf16x8*)&p_lds[w][pin][0];
#pragma unroll
    for (int db = 0; db < 8; ++db)
      oacc[db] = __builtin_amdgcn_mfma_f32_16x16x32_bf16(a1, st[(16 + db) * 64 + lane], oacc[db], 0, 0, 0);
  }
  // --- epilogue
  float linv = 1.f / l_run;
  if (lane < 16) bc[w][lane] = linv;
  f32x4 lv = *(const f32x4*)&bc[w][quad * 4];
  const int ibase = it * 64 + w * 16 + quad * 4;
#pragma unroll
  for (int db = 0; db < 8; ++db)
#pragma unroll
    for (int r = 0; r < 4; ++r)
      atomicAdd(&out[(size_t)(ibase + r) * VDIM + db * 16 + n], oacc[db][r] * lv[r]);
}

extern "C" void kernel_launch(void* const* d_in, const int* in_sizes, int n_in,
                              void* d_out, int out_size, void* d_ws, size_t ws_size,
                              hipStream_t stream) {
  const float* nodes = (const float*)d_in[0];
  const float* pos   = (const float*)d_in[1];
  const float* rot   = (const float*)d_in[2];
  const float* w_n   = (const float*)d_in[3];
  const float* b_n   = (const float*)d_in[4];
  const float* w_p   = (const float*)d_in[5];
  const float* b_p   = (const float*)d_in[6];
  const float* w_r   = (const float*)d_in[7];
  const float* w_v   = (const float*)d_in[8];
  const float* b_v   = (const float*)d_in[9];
  float* out = (float*)d_out;

  k_zero<<<dim3((SEQ * VDIM) / 256), 256, 0, stream>>>(out);
  k_val<<<dim3(12, 128), 256, 0, stream>>>(nodes, w_v, b_v);
  k_kq<<<dim3(128, 2, 3), 256, 0, stream>>>(nodes, pos, rot, w_n, b_n, w_p, b_p, w_r);
  k_attn<<<dim3(32, NHEAD), 256, 0, stream>>>(out);
}

// Round 9
// 180.119 us; speedup vs baseline: 7.6693x; 1.2241x over previous
//
#include <hip/hip_runtime.h>
#include <hip/hip_bf16.h>
#include <math.h>

#define SEQ 2048
#define NHEAD 24     // 3*H
#define CDIM 32
#define VDIM 128

typedef short bf16x8 __attribute__((ext_vector_type(8)));
typedef float f32x4 __attribute__((ext_vector_type(4)));

#define L2E 1.44269504088896f        // log2(e): folded into K so exp2 == exp
#define SQRT_L2E 1.20112240878645f   // sqrt(log2 e): rot logits get squared

#if __has_builtin(__builtin_amdgcn_exp2f)
#define EXP2(x) __builtin_amdgcn_exp2f(x)
#else
#define EXP2(x) exp2f(x)
#endif

// K B-frags, hi/lo split: [g][blk16(128)][part(2)][lane(64)][e(8)]
__device__ unsigned short g_kkp[(size_t)24 * 128 * 2 * 64 * 8];
// Interleaved Q+V staging source: [g][jt(32 x 64j)][frag(24)][lane(64)][e(8)]
//   frag 0..7  = Q A-frags: [jb(4)][hi/lo]
//   frag 8..23 = V B-frags: [jchunk(2)][db(8)]
__device__ unsigned short g_qv[(size_t)24 * 32 * 24 * 64 * 8];

__device__ __forceinline__ unsigned short f2b(float x) {   // RNE f32->bf16
  union { float f; unsigned u; } v; v.f = x;
  unsigned r = v.u + 0x7FFF + ((v.u >> 16) & 1);
  return (unsigned short)(r >> 16);
}
__device__ __forceinline__ float b2f(unsigned short u) {
  union { unsigned u32; float f; } x; x.u32 = ((unsigned)u) << 16; return x.f;
}
__device__ __forceinline__ unsigned pk2(float a, float b) {  // [lo=a, hi=b] bf16 pair
  __hip_bfloat162 t = __float22bfloat162_rn(float2{a, b});
  union { __hip_bfloat162 h; unsigned u; } c; c.h = t; return c.u;
}
__device__ __forceinline__ unsigned long long pack64(const float* p) {
  return ((unsigned long long)pk2(p[2], p[3]) << 32) | pk2(p[0], p[1]);
}
// async global->LDS, 16B/lane
__device__ __forceinline__ void gld16(const unsigned short* g, unsigned short* l) {
  __builtin_amdgcn_global_load_lds(
      (const __attribute__((address_space(1))) unsigned int*)g,
      (__attribute__((address_space(3))) unsigned int*)l, 16, 0, 0);
}

// ---------- fused MFMA projection: C = nodes @ [w_values; w_nodes_kq]^T + bias ----------
// grid (32 row-tiles, 56 col-tiles): bo 0..47 -> values, 48..55 -> nodes k/q.
// hi/lo split on both operands (3 MFMA/k-step) => f32-grade results.
__global__ __launch_bounds__(256) void k_proj(const float* __restrict__ nodes,
                                              const float* __restrict__ w_v,
                                              const float* __restrict__ b_v,
                                              const float* __restrict__ w_n,
                                              const float* __restrict__ b_n) {
  const int jt = blockIdx.x;          // 64-row tile (rows = sequence idx)
  const int bo = blockIdx.y;          // 64-col tile
  const bool is_kq = bo >= 48;
  const float* wsrc = is_kq ? w_n : w_v;
  const float* bsrc = is_kq ? b_n : b_v;
  const int o0 = is_kq ? (bo - 48) * 64 : bo * 64;
  const int tx = threadIdx.x;
  const int w = tx >> 6, lane = tx & 63;
  const int m = lane & 15, quad = lane >> 4;

  __shared__ __align__(16) unsigned short bst[4][4][2][64][8]; // [ob][ks][part][lane][e] 32KB
  __shared__ __align__(16) float res[4][64][20];               // [wave][o_loc][j_loc pad20] 20KB

  // ---- stage B (weights, hi/lo bf16 frags) ----
#pragma unroll
  for (int it = 0; it < 4; ++it) {
    int slot = tx + it * 256;                 // (ob*4+ks)*64 + ls
    int ls = slot & 63, ks = (slot >> 6) & 3, ob = slot >> 8;
    int nn = ls & 15, qq = ls >> 4;
    const float* wp = wsrc + (size_t)(o0 + ob * 16 + nn) * 128 + ks * 32 + qq * 8;
    float4 f0 = *(const float4*)wp;
    float4 f1 = *(const float4*)(wp + 4);
    float ff[8] = {f0.x, f0.y, f0.z, f0.w, f1.x, f1.y, f1.z, f1.w};
    bf16x8 hi, lo;
#pragma unroll
    for (int e = 0; e < 8; ++e) {
      unsigned short h2 = f2b(ff[e]);
      hi[e] = (short)h2;
      lo[e] = (short)f2b(ff[e] - b2f(h2));
    }
    *(bf16x8*)&bst[ob][ks][0][ls][0] = hi;
    *(bf16x8*)&bst[ob][ks][1][ls][0] = lo;
  }
  // ---- A frags: wave's 16 rows, hi/lo ----
  bf16x8 ah[4], al[4];
  const float* ap = nodes + (size_t)(jt * 64 + w * 16 + m) * 128 + quad * 8;
#pragma unroll
  for (int ks = 0; ks < 4; ++ks) {
    float4 f0 = *(const float4*)(ap + ks * 32);
    float4 f1 = *(const float4*)(ap + ks * 32 + 4);
    float ff[8] = {f0.x, f0.y, f0.z, f0.w, f1.x, f1.y, f1.z, f1.w};
#pragma unroll
    for (int e = 0; e < 8; ++e) {
      unsigned short h2 = f2b(ff[e]);
      ah[ks][e] = (short)h2;
      al[ks][e] = (short)f2b(ff[e] - b2f(h2));
    }
  }
  __syncthreads();
  // ---- MFMA: C[ob] = 16 rows(j) x 16 cols(o) ----
  f32x4 C[4];
#pragma unroll
  for (int ob = 0; ob < 4; ++ob) {
    f32x4 acc = {0.f, 0.f, 0.f, 0.f};
#pragma unroll
    for (int ks = 0; ks < 4; ++ks) {
      bf16x8 bh = *(const bf16x8*)&bst[ob][ks][0][lane][0];
      bf16x8 bl = *(const bf16x8*)&bst[ob][ks][1][lane][0];
      acc = __builtin_amdgcn_mfma_f32_16x16x32_bf16(ah[ks], bh, acc, 0, 0, 0);
      acc = __builtin_amdgcn_mfma_f32_16x16x32_bf16(al[ks], bh, acc, 0, 0, 0);
      acc = __builtin_amdgcn_mfma_f32_16x16x32_bf16(ah[ks], bl, acc, 0, 0, 0);
    }
    C[ob] = acc;
  }
  // ---- C + bias -> per-wave res (C: col=lane&15 -> o, row=quad*4+r -> j) ----
#pragma unroll
  for (int ob = 0; ob < 4; ++ob) {
    float bias = bsrc[o0 + ob * 16 + m];
#pragma unroll
    for (int r = 0; r < 4; ++r)
      res[w][ob * 16 + m][quad * 4 + r] = C[ob][r] + bias;
  }
  // per-wave private res; DS in-order within wave -> no barrier needed
  if (!is_kq) {
    // ---- V epilogue: single bf16, frag layout ----
    const int g = bo >> 1, dbb = (bo & 1) * 4;
    const int jc = w >> 1, khb = (w & 1) * 2;
    const int rowq = quad;              // db sub-index (4 per 64-col tile)
#pragma unroll
    for (int oct = 0; oct < 2; ++oct) {
      f32x4 v0 = *(const f32x4*)&res[w][rowq * 16 + m][oct * 8];
      f32x4 v1 = *(const f32x4*)&res[w][rowq * 16 + m][oct * 8 + 4];
      bf16x8 pk;
#pragma unroll
      for (int e = 0; e < 4; ++e) {
        pk[e]     = (short)f2b(v0[e]);
        pk[4 + e] = (short)f2b(v1[e]);
      }
      ((bf16x8*)g_qv)[(((size_t)g * 32 + jt) * 24 + 8 + jc * 8 + dbb + rowq) * 64
                      + (khb + oct) * 16 + m] = pk;
    }
  } else {
    // ---- nodes k/q epilogue: hi/lo split, L2E folded into K ----
    const int h = bo - 48;
    const int rowq = quad;              // c-octet
    {   // K: c0 = rowq*8+e
      bf16x8 hi, lo;
#pragma unroll
      for (int e = 0; e < 8; ++e) {
        float v = res[w][rowq * 8 + e][m] * L2E;
        unsigned short h2 = f2b(v);
        hi[e] = (short)h2;
        lo[e] = (short)f2b(v - b2f(h2));
      }
      size_t base = ((size_t)(h * 128 + jt * 4 + w) * 2) * 512 + (size_t)(rowq * 16 + m) * 8;
      *(bf16x8*)(g_kkp + base) = hi;
      *(bf16x8*)(g_kkp + base + 512) = lo;
    }
    {   // Q: c0 = 32 + rowq*8+e
      bf16x8 hi, lo;
#pragma unroll
      for (int e = 0; e < 8; ++e) {
        float v = res[w][32 + rowq * 8 + e][m];
        unsigned short h2 = f2b(v);
        hi[e] = (short)h2;
        lo[e] = (short)f2b(v - b2f(h2));
      }
      size_t base = (((size_t)h * 32 + jt) * 24 + w * 2) * 512 + (size_t)(rowq * 16 + m) * 8;
      *(bf16x8*)(g_qv + base) = hi;
      *(bf16x8*)(g_qv + base + 512) = lo;
    }
  }
}

// ---------- pos/rot k/q repack helper ----------
__device__ __forceinline__ void repack_store(const unsigned* __restrict__ res,
                                             int oh, int it16, int tx, int head_base) {
#pragma unroll
  for (int t2 = 0; t2 < 2; ++t2) {
    int cid = tx + t2 * 256;           // 0..511
    int hl  = cid >> 7;                // local head 0..3
    int kq  = (cid >> 6) & 1;          // 0=k 1=q
    int row = cid & 63;                // frag lane
    int m = row & 15, kb = row >> 4;
    int ob = hl * 64 + kq * 32 + kb * 8;
    bf16x8 hi, lo;
#pragma unroll
    for (int e = 0; e < 8; ++e) {
      unsigned pk = res[(ob + e) * 17 + m];
      hi[e] = (short)(pk >> 16);
      lo[e] = (short)(pk & 0xffff);
    }
    int gh = head_base + oh * 4 + hl;
    if (kq == 0) {
      size_t base = ((size_t)(gh * 128 + it16) * 2) * 512 + (size_t)row * 8;
      *(bf16x8*)(g_kkp + base) = hi;
      *(bf16x8*)(g_kkp + base + 512) = lo;
    } else {
      int jt = it16 >> 2, jb = it16 & 3;
      size_t base = (((size_t)gh * 32 + jt) * 24 + jb * 2) * 512 + (size_t)row * 8;
      *(bf16x8*)(g_qv + base) = hi;
      *(bf16x8*)(g_qv + base + 512) = lo;
    }
  }
}

// grid (128, 2, 2): z = 0 pos (heads 8..15), 1 rot (heads 16..23)
__global__ __launch_bounds__(256) void k_posrot(const float* __restrict__ pos,
                                                const float* __restrict__ rot,
                                                const float* __restrict__ w_p,
                                                const float* __restrict__ b_p,
                                                const float* __restrict__ w_r) {
  const int it16 = blockIdx.x;
  const int oh   = blockIdx.y;
  const int br   = blockIdx.z;
  const int tx = threadIdx.x;
  const int i0 = it16 * 16;

  __shared__ float pf_sh[16][8];
  __shared__ float rr_sh[16][4];
  __shared__ unsigned res[256 * 17];

  if (br == 0) {
    if (tx < 48) {
      int r = tx / 3, t = tx - r * 3;
      float p = pos[(i0 + r) * 3 + t];
      pf_sh[r][t]     = cosf(6.283185307179586f * p);
      pf_sh[r][t + 3] = sinf(6.283185307179586f * p);
    }
  } else {
    if (tx < 64) {
      int r = tx >> 2, t = tx & 3;
      rr_sh[r][t] = rot[(i0 + r) * 4 + t];
    }
  }
  __syncthreads();

  const int og = tx & 63, ig = tx >> 6;

  if (br == 0) {
#pragma unroll
    for (int oo = 0; oo < 4; ++oo) {
      int o = oh * 256 + oo * 64 + og;
      float bb = b_p[o];
      float w0 = w_p[o * 6 + 0], w1 = w_p[o * 6 + 1], w2 = w_p[o * 6 + 2];
      float w3 = w_p[o * 6 + 3], w4 = w_p[o * 6 + 4], w5 = w_p[o * 6 + 5];
      float sc = ((o & 63) < 32) ? L2E : 1.f;
#pragma unroll
      for (int ii = 0; ii < 4; ++ii) {
        int i = ig * 4 + ii;
        float v = bb + pf_sh[i][0] * w0 + pf_sh[i][1] * w1 + pf_sh[i][2] * w2
                     + pf_sh[i][3] * w3 + pf_sh[i][4] * w4 + pf_sh[i][5] * w5;
        v *= sc;
        unsigned short hi = f2b(v);
        unsigned short lo = f2b(v - b2f(hi));
        res[(oo * 64 + og) * 17 + i] = ((unsigned)hi << 16) | lo;
      }
    }
  } else {
#pragma unroll
    for (int oo = 0; oo < 4; ++oo) {
      int o = oh * 256 + oo * 64 + og;
      float w0 = w_r[o * 4 + 0], w1 = w_r[o * 4 + 1], w2 = w_r[o * 4 + 2], w3 = w_r[o * 4 + 3];
      float sc = ((o & 63) < 32) ? SQRT_L2E : 1.f;
#pragma unroll
      for (int ii = 0; ii < 4; ++ii) {
        int i = ig * 4 + ii;
        float v = (rr_sh[i][0] * w0 + rr_sh[i][1] * w1 + rr_sh[i][2] * w2 + rr_sh[i][3] * w3) * sc;
        unsigned short hi = f2b(v);
        unsigned short lo = f2b(v - b2f(hi));
        res[(oo * 64 + og) * 17 + i] = ((unsigned)hi << 16) | lo;
      }
    }
  }
  __syncthreads();
  repack_store(res, oh, it16, tx, 8 + br * 8);
}

// ---------- zero output ----------
__global__ __launch_bounds__(256) void k_zero(float* __restrict__ out) {
  out[blockIdx.x * 256 + threadIdx.x] = 0.f;
}

// ---------- MFMA flash attention: 64 j per iter, LDS-staged Q+V (unchanged r8) ----------
__global__ __launch_bounds__(256) void k_attn(float* __restrict__ out) {
  const int it = blockIdx.x;            // 0..31
  const int g  = blockIdx.y;            // 0..23
  const int tx = threadIdx.x;
  const int w = tx >> 6, lane = tx & 63;
  const int quad = lane >> 4, n = lane & 15;
  const int iblk = it * 4 + w;

  __shared__ __align__(16) unsigned short stage[2][24][64][8];   // 48 KB
  __shared__ __align__(16) unsigned long long p_lds[4][64][2];   // 4 KB
  __shared__ __align__(16) float bc[4][16];

  const bf16x8* kp = (const bf16x8*)g_kkp + (size_t)(g * 128 + iblk) * 2 * 64;
  const bf16x8 khi = kp[lane], klo = kp[64 + lane];

  f32x4 oacc[8];
#pragma unroll
  for (int db = 0; db < 8; ++db)
#pragma unroll
    for (int r = 0; r < 4; ++r) oacc[db][r] = 0.f;

  float m_run = -3.0e38f, l_run = 0.f;
  const bool is_rot = (g >= 16);
  const int pin = (lane & 56) | ((lane ^ (lane >> 3)) & 7);
  const int wrow0 = (quad >> 1) * 16 + n;
  const int wrow1 = wrow0 + 32;
  const int pr0 = (wrow0 & 56) | ((wrow0 ^ (wrow0 >> 3)) & 7);
  const int pr1 = (wrow1 & 56) | ((wrow1 ^ (wrow1 >> 3)) & 7);
  const int whalf = quad & 1;

  const unsigned short* qv = g_qv + ((size_t)g * 32 * 24 + w * 6) * 512 + (size_t)lane * 8;

#define STG(nb)                                          \
  { gld16(qv,             &stage[nb][w * 6 + 0][0][0]);  \
    gld16(qv + 512,       &stage[nb][w * 6 + 1][0][0]);  \
    gld16(qv + 1024,      &stage[nb][w * 6 + 2][0][0]);  \
    gld16(qv + 1536,      &stage[nb][w * 6 + 3][0][0]);  \
    gld16(qv + 2048,      &stage[nb][w * 6 + 4][0][0]);  \
    gld16(qv + 2560,      &stage[nb][w * 6 + 5][0][0]); }

  STG(0)

  for (int jt = 0; jt < 32; ++jt) {
    const int buf = jt & 1;
    __syncthreads();
    qv += 24 * 512;
    if (jt < 31) STG(buf ^ 1)

    const bf16x8* st = (const bf16x8*)&stage[buf][0][0][0];
    f32x4 S[4];
#pragma unroll
    for (int jb = 0; jb < 4; ++jb) {
      bf16x8 qh = st[(jb * 2) * 64 + lane], ql = st[(jb * 2 + 1) * 64 + lane];
      f32x4 a = {0.f, 0.f, 0.f, 0.f};
      a = __builtin_amdgcn_mfma_f32_16x16x32_bf16(qh, khi, a, 0, 0, 0);
      a = __builtin_amdgcn_mfma_f32_16x16x32_bf16(ql, khi, a, 0, 0, 0);
      a = __builtin_amdgcn_mfma_f32_16x16x32_bf16(qh, klo, a, 0, 0, 0);
      S[jb] = a;
    }
    if (is_rot) {
#pragma unroll
      for (int jb = 0; jb < 4; ++jb)
#pragma unroll
        for (int r = 0; r < 4; ++r) S[jb][r] *= S[jb][r];
    }
    float mb = S[0][0];
#pragma unroll
    for (int jb = 0; jb < 4; ++jb)
#pragma unroll
      for (int r = 0; r < 4; ++r) mb = fmaxf(mb, S[jb][r]);
    mb = fmaxf(mb, __shfl_xor(mb, 16));
    mb = fmaxf(mb, __shfl_xor(mb, 32));
    if (__ballot(mb > m_run)) {
      float m_new = fmaxf(m_run, mb);
      float alpha = EXP2(m_run - m_new);
      l_run *= alpha;
      m_run = m_new;
      if (lane < 16) bc[w][lane] = alpha;
      f32x4 av = *(const f32x4*)&bc[w][quad * 4];
#pragma unroll
      for (int db = 0; db < 8; ++db) {
        oacc[db][0] *= av[0]; oacc[db][1] *= av[1];
        oacc[db][2] *= av[2]; oacc[db][3] *= av[3];
      }
    }
    float p[4][4];
    float s = 0.f;
#pragma unroll
    for (int jb = 0; jb < 4; ++jb)
#pragma unroll
      for (int r = 0; r < 4; ++r) {
        p[jb][r] = EXP2(S[jb][r] - m_run);
        s += p[jb][r];
      }
    s += __shfl_xor(s, 16);
    s += __shfl_xor(s, 32);
    l_run += s;
    p_lds[w][pr0][whalf] = pack64(p[0]);
    p_lds[w][pr1][whalf] = pack64(p[1]);
    bf16x8 a0 = *(const bf16x8*)&p_lds[w][pin][0];
#pragma unroll
    for (int db = 0; db < 8; ++db)
      oacc[db] = __builtin_amdgcn_mfma_f32_16x16x32_bf16(a0, st[(8 + db) * 64 + lane], oacc[db], 0, 0, 0);
    p_lds[w][pr0][whalf] = pack64(p[2]);
    p_lds[w][pr1][whalf] = pack64(p[3]);
    bf16x8 a1 = *(const bf16x8*)&p_lds[w][pin][0];
#pragma unroll
    for (int db = 0; db < 8; ++db)
      oacc[db] = __builtin_amdgcn_mfma_f32_16x16x32_bf16(a1, st[(16 + db) * 64 + lane], oacc[db], 0, 0, 0);
  }
  float linv = 1.f / l_run;
  if (lane < 16) bc[w][lane] = linv;
  f32x4 lv = *(const f32x4*)&bc[w][quad * 4];
  const int ibase = it * 64 + w * 16 + quad * 4;
#pragma unroll
  for (int db = 0; db < 8; ++db)
#pragma unroll
    for (int r = 0; r < 4; ++r)
      atomicAdd(&out[(size_t)(ibase + r) * VDIM + db * 16 + n], oacc[db][r] * lv[r]);
}

extern "C" void kernel_launch(void* const* d_in, const int* in_sizes, int n_in,
                              void* d_out, int out_size, void* d_ws, size_t ws_size,
                              hipStream_t stream) {
  const float* nodes = (const float*)d_in[0];
  const float* pos   = (const float*)d_in[1];
  const float* rot   = (const float*)d_in[2];
  const float* w_n   = (const float*)d_in[3];
  const float* b_n   = (const float*)d_in[4];
  const float* w_p   = (const float*)d_in[5];
  const float* b_p   = (const float*)d_in[6];
  const float* w_r   = (const float*)d_in[7];
  const float* w_v   = (const float*)d_in[8];
  const float* b_v   = (const float*)d_in[9];
  float* out = (float*)d_out;

  k_zero<<<dim3((SEQ * VDIM) / 256), 256, 0, stream>>>(out);
  k_proj<<<dim3(32, 56), 256, 0, stream>>>(nodes, w_v, b_v, w_n, b_n);
  k_posrot<<<dim3(128, 2, 2), 256, 0, stream>>>(pos, rot, w_p, b_p, w_r);
  k_attn<<<dim3(32, NHEAD), 256, 0, stream>>>(out);
}

// Round 10
// 174.741 us; speedup vs baseline: 7.9053x; 1.0308x over previous
//
#include <hip/hip_runtime.h>
#include <hip/hip_bf16.h>
#include <math.h>

#define SEQ 2048
#define NHEAD 24     // 3*H
#define CDIM 32
#define VDIM 128

typedef short bf16x8 __attribute__((ext_vector_type(8)));
typedef float f32x4 __attribute__((ext_vector_type(4)));

#define L2E 1.44269504088896f        // log2(e): folded into K so exp2 == exp
#define SQRT_L2E 1.20112240878645f   // sqrt(log2 e): rot logits get squared

#if __has_builtin(__builtin_amdgcn_exp2f)
#define EXP2(x) __builtin_amdgcn_exp2f(x)
#else
#define EXP2(x) exp2f(x)
#endif

// K B-frags, hi/lo split: [g][blk16(128)][part(2)][lane(64)][e(8)]
__device__ unsigned short g_kkp[(size_t)24 * 128 * 2 * 64 * 8];
// Interleaved Q+V staging source: [g][jt(32 x 64j)][frag(24)][lane(64)][e(8)]
__device__ unsigned short g_qv[(size_t)24 * 32 * 24 * 64 * 8];
// Pre-converted hi/lo frag operands for k_proj:
// weights (w_values||w_nodes_kq rows, 3584 cols of C): [fg(224*4)][part(2)][lane][e]
__device__ unsigned short g_wp[(size_t)224 * 4 * 2 * 64 * 8];
// nodes A-frags: [fg(128*4)][part(2)][lane][e]
__device__ unsigned short g_np[(size_t)128 * 4 * 2 * 64 * 8];

__device__ __forceinline__ unsigned short f2b(float x) {   // RNE f32->bf16
  union { float f; unsigned u; } v; v.f = x;
  unsigned r = v.u + 0x7FFF + ((v.u >> 16) & 1);
  return (unsigned short)(r >> 16);
}
__device__ __forceinline__ float b2f(unsigned short u) {
  union { unsigned u32; float f; } x; x.u32 = ((unsigned)u) << 16; return x.f;
}
__device__ __forceinline__ unsigned pk2(float a, float b) {  // [lo=a, hi=b] bf16 pair
  __hip_bfloat162 t = __float22bfloat162_rn(float2{a, b});
  union { __hip_bfloat162 h; unsigned u; } c; c.h = t; return c.u;
}
__device__ __forceinline__ unsigned long long pack64(const float* p) {
  return ((unsigned long long)pk2(p[2], p[3]) << 32) | pk2(p[0], p[1]);
}
// async global->LDS, 16B/lane
__device__ __forceinline__ void gld16(const unsigned short* g, unsigned short* l) {
  __builtin_amdgcn_global_load_lds(
      (const __attribute__((address_space(1))) unsigned int*)g,
      (__attribute__((address_space(3))) unsigned int*)l, 16, 0, 0);
}

// ---------- one-shot hi/lo conversion of weights + nodes into frag layouts ----------
// blocks 0..223: weights (fg = colblk*4+ks); blocks 224..351: nodes (fg2 = rowblk*4+ks)
__global__ __launch_bounds__(256) void k_prep(const float* __restrict__ nodes,
                                              const float* __restrict__ w_v,
                                              const float* __restrict__ w_n) {
  const int tid = blockIdx.x * 256 + threadIdx.x;
  const int fg = tid >> 6, lane = tid & 63;
  const int e0 = (lane >> 4) * 8;
  const float* p;
  unsigned short* dst;
  if (blockIdx.x < 224) {
    const int colblk = fg >> 2, ks = fg & 3;
    const int ocol = colblk * 16 + (lane & 15);
    const float* src = (ocol < 3072) ? (w_v + (size_t)ocol * 128)
                                     : (w_n + (size_t)(ocol - 3072) * 128);
    p = src + ks * 32 + e0;
    dst = g_wp + (size_t)fg * 1024;
  } else {
    const int fg2 = fg - 224 * 4;        // 0..511
    const int rowblk = fg2 >> 2, ks = fg2 & 3;
    p = nodes + (size_t)(rowblk * 16 + (lane & 15)) * 128 + ks * 32 + e0;
    dst = g_np + (size_t)fg2 * 1024;
  }
  float4 f0 = *(const float4*)p;
  float4 f1 = *(const float4*)(p + 4);
  float ff[8] = {f0.x, f0.y, f0.z, f0.w, f1.x, f1.y, f1.z, f1.w};
  bf16x8 hi, lo;
#pragma unroll
  for (int e = 0; e < 8; ++e) {
    unsigned short h2 = f2b(ff[e]);
    hi[e] = (short)h2;
    lo[e] = (short)f2b(ff[e] - b2f(h2));
  }
  *(bf16x8*)(dst + (size_t)lane * 8) = hi;          // part 0
  *(bf16x8*)(dst + 512 + (size_t)lane * 8) = lo;    // part 1
}

// ---------- fused MFMA projection: C = nodes @ [w_values; w_nodes_kq]^T + bias ----------
// grid (32 row-tiles, 56 col-tiles): bo 0..47 -> values, 48..55 -> nodes k/q.
__global__ __launch_bounds__(256) void k_proj(const float* __restrict__ b_v,
                                              const float* __restrict__ b_n) {
  const int jt = blockIdx.x;          // 64-row tile
  const int bo = blockIdx.y;          // 64-col tile
  const bool is_kq = bo >= 48;
  const float* bsrc = is_kq ? b_n : b_v;
  const int o0b = is_kq ? (bo - 48) * 64 : bo * 64;
  const int tx = threadIdx.x;
  const int w = tx >> 6, lane = tx & 63;
  const int m = lane & 15, quad = lane >> 4;

  __shared__ __align__(16) unsigned short bst[32][64][8];   // 32 KB, frag f = ob*8+ks*2+part
  __shared__ __align__(16) float res[4][64][20];            // [wave][o_loc][j_loc pad20]

  // ---- stage weight frags async: wave w stages f = w*8..w*8+7 (contiguous globally) ----
  const unsigned short* wp = g_wp + ((size_t)bo * 32 + w * 8) * 512 + (size_t)lane * 8;
#pragma unroll
  for (int s = 0; s < 8; ++s)
    gld16(wp + s * 512, &bst[w * 8 + s][0][0]);

  // ---- A frags: register loads from pre-converted g_np ----
  bf16x8 ah[4], al[4];
  const unsigned short* np = g_np + (size_t)(jt * 4 + w) * 4096 + (size_t)lane * 8;
#pragma unroll
  for (int ks = 0; ks < 4; ++ks) {
    ah[ks] = *(const bf16x8*)(np + ks * 1024);
    al[ks] = *(const bf16x8*)(np + ks * 1024 + 512);
  }
  __syncthreads();   // drains gld16 vmcnt before barrier

  // ---- MFMA: C[ob] = 16 rows(j) x 16 cols(o), 3-term hi/lo ----
  f32x4 C[4];
#pragma unroll
  for (int ob = 0; ob < 4; ++ob) {
    f32x4 acc = {0.f, 0.f, 0.f, 0.f};
#pragma unroll
    for (int ks = 0; ks < 4; ++ks) {
      bf16x8 bh = *(const bf16x8*)&bst[ob * 8 + ks * 2][lane][0];
      bf16x8 bl = *(const bf16x8*)&bst[ob * 8 + ks * 2 + 1][lane][0];
      acc = __builtin_amdgcn_mfma_f32_16x16x32_bf16(ah[ks], bh, acc, 0, 0, 0);
      acc = __builtin_amdgcn_mfma_f32_16x16x32_bf16(al[ks], bh, acc, 0, 0, 0);
      acc = __builtin_amdgcn_mfma_f32_16x16x32_bf16(ah[ks], bl, acc, 0, 0, 0);
    }
    C[ob] = acc;
  }
  // ---- C + bias -> per-wave res (C: col=lane&15 -> o, row=quad*4+r -> j) ----
#pragma unroll
  for (int ob = 0; ob < 4; ++ob) {
    float bias = bsrc[o0b + ob * 16 + m];
#pragma unroll
    for (int r = 0; r < 4; ++r)
      res[w][ob * 16 + m][quad * 4 + r] = C[ob][r] + bias;
  }
  // per-wave private res; DS in-order within wave -> no barrier needed
  if (!is_kq) {
    // ---- V epilogue: single bf16, frag layout (validated r9) ----
    const int g = bo >> 1, dbb = (bo & 1) * 4;
    const int jc = w >> 1, khb = (w & 1) * 2;
    const int rowq = quad;
#pragma unroll
    for (int oct = 0; oct < 2; ++oct) {
      f32x4 v0 = *(const f32x4*)&res[w][rowq * 16 + m][oct * 8];
      f32x4 v1 = *(const f32x4*)&res[w][rowq * 16 + m][oct * 8 + 4];
      bf16x8 pk;
#pragma unroll
      for (int e = 0; e < 4; ++e) {
        pk[e]     = (short)f2b(v0[e]);
        pk[4 + e] = (short)f2b(v1[e]);
      }
      ((bf16x8*)g_qv)[(((size_t)g * 32 + jt) * 24 + 8 + jc * 8 + dbb + rowq) * 64
                      + (khb + oct) * 16 + m] = pk;
    }
  } else {
    // ---- nodes k/q epilogue: hi/lo split, L2E folded into K (validated r9) ----
    const int h = bo - 48;
    const int rowq = quad;
    {   // K
      bf16x8 hi, lo;
#pragma unroll
      for (int e = 0; e < 8; ++e) {
        float v = res[w][rowq * 8 + e][m] * L2E;
        unsigned short h2 = f2b(v);
        hi[e] = (short)h2;
        lo[e] = (short)f2b(v - b2f(h2));
      }
      size_t base = ((size_t)(h * 128 + jt * 4 + w) * 2) * 512 + (size_t)(rowq * 16 + m) * 8;
      *(bf16x8*)(g_kkp + base) = hi;
      *(bf16x8*)(g_kkp + base + 512) = lo;
    }
    {   // Q
      bf16x8 hi, lo;
#pragma unroll
      for (int e = 0; e < 8; ++e) {
        float v = res[w][32 + rowq * 8 + e][m];
        unsigned short h2 = f2b(v);
        hi[e] = (short)h2;
        lo[e] = (short)f2b(v - b2f(h2));
      }
      size_t base = (((size_t)h * 32 + jt) * 24 + w * 2) * 512 + (size_t)(rowq * 16 + m) * 8;
      *(bf16x8*)(g_qv + base) = hi;
      *(bf16x8*)(g_qv + base + 512) = lo;
    }
  }
}

// ---------- pos/rot k/q repack helper ----------
__device__ __forceinline__ void repack_store(const unsigned* __restrict__ res,
                                             int oh, int it16, int tx, int head_base) {
#pragma unroll
  for (int t2 = 0; t2 < 2; ++t2) {
    int cid = tx + t2 * 256;
    int hl  = cid >> 7;
    int kq  = (cid >> 6) & 1;
    int row = cid & 63;
    int m = row & 15, kb = row >> 4;
    int ob = hl * 64 + kq * 32 + kb * 8;
    bf16x8 hi, lo;
#pragma unroll
    for (int e = 0; e < 8; ++e) {
      unsigned pk = res[(ob + e) * 17 + m];
      hi[e] = (short)(pk >> 16);
      lo[e] = (short)(pk & 0xffff);
    }
    int gh = head_base + oh * 4 + hl;
    if (kq == 0) {
      size_t base = ((size_t)(gh * 128 + it16) * 2) * 512 + (size_t)row * 8;
      *(bf16x8*)(g_kkp + base) = hi;
      *(bf16x8*)(g_kkp + base + 512) = lo;
    } else {
      int jt = it16 >> 2, jb = it16 & 3;
      size_t base = (((size_t)gh * 32 + jt) * 24 + jb * 2) * 512 + (size_t)row * 8;
      *(bf16x8*)(g_qv + base) = hi;
      *(bf16x8*)(g_qv + base + 512) = lo;
    }
  }
}

// grid (128, 2, 2): z = 0 pos (heads 8..15), 1 rot (heads 16..23)
__global__ __launch_bounds__(256) void k_posrot(const float* __restrict__ pos,
                                                const float* __restrict__ rot,
                                                const float* __restrict__ w_p,
                                                const float* __restrict__ b_p,
                                                const float* __restrict__ w_r) {
  const int it16 = blockIdx.x;
  const int oh   = blockIdx.y;
  const int br   = blockIdx.z;
  const int tx = threadIdx.x;
  const int i0 = it16 * 16;

  __shared__ float pf_sh[16][8];
  __shared__ float rr_sh[16][4];
  __shared__ unsigned res[256 * 17];

  if (br == 0) {
    if (tx < 48) {
      int r = tx / 3, t = tx - r * 3;
      float p = pos[(i0 + r) * 3 + t];
      pf_sh[r][t]     = cosf(6.283185307179586f * p);
      pf_sh[r][t + 3] = sinf(6.283185307179586f * p);
    }
  } else {
    if (tx < 64) {
      int r = tx >> 2, t = tx & 3;
      rr_sh[r][t] = rot[(i0 + r) * 4 + t];
    }
  }
  __syncthreads();

  const int og = tx & 63, ig = tx >> 6;

  if (br == 0) {
#pragma unroll
    for (int oo = 0; oo < 4; ++oo) {
      int o = oh * 256 + oo * 64 + og;
      float bb = b_p[o];
      float w0 = w_p[o * 6 + 0], w1 = w_p[o * 6 + 1], w2 = w_p[o * 6 + 2];
      float w3 = w_p[o * 6 + 3], w4 = w_p[o * 6 + 4], w5 = w_p[o * 6 + 5];
      float sc = ((o & 63) < 32) ? L2E : 1.f;
#pragma unroll
      for (int ii = 0; ii < 4; ++ii) {
        int i = ig * 4 + ii;
        float v = bb + pf_sh[i][0] * w0 + pf_sh[i][1] * w1 + pf_sh[i][2] * w2
                     + pf_sh[i][3] * w3 + pf_sh[i][4] * w4 + pf_sh[i][5] * w5;
        v *= sc;
        unsigned short hi = f2b(v);
        unsigned short lo = f2b(v - b2f(hi));
        res[(oo * 64 + og) * 17 + i] = ((unsigned)hi << 16) | lo;
      }
    }
  } else {
#pragma unroll
    for (int oo = 0; oo < 4; ++oo) {
      int o = oh * 256 + oo * 64 + og;
      float w0 = w_r[o * 4 + 0], w1 = w_r[o * 4 + 1], w2 = w_r[o * 4 + 2], w3 = w_r[o * 4 + 3];
      float sc = ((o & 63) < 32) ? SQRT_L2E : 1.f;
#pragma unroll
      for (int ii = 0; ii < 4; ++ii) {
        int i = ig * 4 + ii;
        float v = (rr_sh[i][0] * w0 + rr_sh[i][1] * w1 + rr_sh[i][2] * w2 + rr_sh[i][3] * w3) * sc;
        unsigned short hi = f2b(v);
        unsigned short lo = f2b(v - b2f(hi));
        res[(oo * 64 + og) * 17 + i] = ((unsigned)hi << 16) | lo;
      }
    }
  }
  __syncthreads();
  repack_store(res, oh, it16, tx, 8 + br * 8);
}

// ---------- zero output ----------
__global__ __launch_bounds__(256) void k_zero(float* __restrict__ out) {
  out[blockIdx.x * 256 + threadIdx.x] = 0.f;
}

// ---------- MFMA flash attention: 64 j per iter, LDS-staged Q+V (unchanged r8) ----------
__global__ __launch_bounds__(256) void k_attn(float* __restrict__ out) {
  const int it = blockIdx.x;            // 0..31
  const int g  = blockIdx.y;            // 0..23
  const int tx = threadIdx.x;
  const int w = tx >> 6, lane = tx & 63;
  const int quad = lane >> 4, n = lane & 15;
  const int iblk = it * 4 + w;

  __shared__ __align__(16) unsigned short stage[2][24][64][8];   // 48 KB
  __shared__ __align__(16) unsigned long long p_lds[4][64][2];   // 4 KB
  __shared__ __align__(16) float bc[4][16];

  const bf16x8* kp = (const bf16x8*)g_kkp + (size_t)(g * 128 + iblk) * 2 * 64;
  const bf16x8 khi = kp[lane], klo = kp[64 + lane];

  f32x4 oacc[8];
#pragma unroll
  for (int db = 0; db < 8; ++db)
#pragma unroll
    for (int r = 0; r < 4; ++r) oacc[db][r] = 0.f;

  float m_run = -3.0e38f, l_run = 0.f;
  const bool is_rot = (g >= 16);
  const int pin = (lane & 56) | ((lane ^ (lane >> 3)) & 7);
  const int wrow0 = (quad >> 1) * 16 + n;
  const int wrow1 = wrow0 + 32;
  const int pr0 = (wrow0 & 56) | ((wrow0 ^ (wrow0 >> 3)) & 7);
  const int pr1 = (wrow1 & 56) | ((wrow1 ^ (wrow1 >> 3)) & 7);
  const int whalf = quad & 1;

  const unsigned short* qv = g_qv + ((size_t)g * 32 * 24 + w * 6) * 512 + (size_t)lane * 8;

#define STG(nb)                                          \
  { gld16(qv,             &stage[nb][w * 6 + 0][0][0]);  \
    gld16(qv + 512,       &stage[nb][w * 6 + 1][0][0]);  \
    gld16(qv + 1024,      &stage[nb][w * 6 + 2][0][0]);  \
    gld16(qv + 1536,      &stage[nb][w * 6 + 3][0][0]);  \
    gld16(qv + 2048,      &stage[nb][w * 6 + 4][0][0]);  \
    gld16(qv + 2560,      &stage[nb][w * 6 + 5][0][0]); }

  STG(0)

  for (int jt = 0; jt < 32; ++jt) {
    const int buf = jt & 1;
    __syncthreads();
    qv += 24 * 512;
    if (jt < 31) STG(buf ^ 1)

    const bf16x8* st = (const bf16x8*)&stage[buf][0][0][0];
    f32x4 S[4];
#pragma unroll
    for (int jb = 0; jb < 4; ++jb) {
      bf16x8 qh = st[(jb * 2) * 64 + lane], ql = st[(jb * 2 + 1) * 64 + lane];
      f32x4 a = {0.f, 0.f, 0.f, 0.f};
      a = __builtin_amdgcn_mfma_f32_16x16x32_bf16(qh, khi, a, 0, 0, 0);
      a = __builtin_amdgcn_mfma_f32_16x16x32_bf16(ql, khi, a, 0, 0, 0);
      a = __builtin_amdgcn_mfma_f32_16x16x32_bf16(qh, klo, a, 0, 0, 0);
      S[jb] = a;
    }
    if (is_rot) {
#pragma unroll
      for (int jb = 0; jb < 4; ++jb)
#pragma unroll
        for (int r = 0; r < 4; ++r) S[jb][r] *= S[jb][r];
    }
    float mb = S[0][0];
#pragma unroll
    for (int jb = 0; jb < 4; ++jb)
#pragma unroll
      for (int r = 0; r < 4; ++r) mb = fmaxf(mb, S[jb][r]);
    mb = fmaxf(mb, __shfl_xor(mb, 16));
    mb = fmaxf(mb, __shfl_xor(mb, 32));
    if (__ballot(mb > m_run)) {
      float m_new = fmaxf(m_run, mb);
      float alpha = EXP2(m_run - m_new);
      l_run *= alpha;
      m_run = m_new;
      if (lane < 16) bc[w][lane] = alpha;
      f32x4 av = *(const f32x4*)&bc[w][quad * 4];
#pragma unroll
      for (int db = 0; db < 8; ++db) {
        oacc[db][0] *= av[0]; oacc[db][1] *= av[1];
        oacc[db][2] *= av[2]; oacc[db][3] *= av[3];
      }
    }
    float p[4][4];
    float s = 0.f;
#pragma unroll
    for (int jb = 0; jb < 4; ++jb)
#pragma unroll
      for (int r = 0; r < 4; ++r) {
        p[jb][r] = EXP2(S[jb][r] - m_run);
        s += p[jb][r];
      }
    s += __shfl_xor(s, 16);
    s += __shfl_xor(s, 32);
    l_run += s;
    p_lds[w][pr0][whalf] = pack64(p[0]);
    p_lds[w][pr1][whalf] = pack64(p[1]);
    bf16x8 a0 = *(const bf16x8*)&p_lds[w][pin][0];
#pragma unroll
    for (int db = 0; db < 8; ++db)
      oacc[db] = __builtin_amdgcn_mfma_f32_16x16x32_bf16(a0, st[(8 + db) * 64 + lane], oacc[db], 0, 0, 0);
    p_lds[w][pr0][whalf] = pack64(p[2]);
    p_lds[w][pr1][whalf] = pack64(p[3]);
    bf16x8 a1 = *(const bf16x8*)&p_lds[w][pin][0];
#pragma unroll
    for (int db = 0; db < 8; ++db)
      oacc[db] = __builtin_amdgcn_mfma_f32_16x16x32_bf16(a1, st[(16 + db) * 64 + lane], oacc[db], 0, 0, 0);
  }
  float linv = 1.f / l_run;
  if (lane < 16) bc[w][lane] = linv;
  f32x4 lv = *(const f32x4*)&bc[w][quad * 4];
  const int ibase = it * 64 + w * 16 + quad * 4;
#pragma unroll
  for (int db = 0; db < 8; ++db)
#pragma unroll
    for (int r = 0; r < 4; ++r)
      atomicAdd(&out[(size_t)(ibase + r) * VDIM + db * 16 + n], oacc[db][r] * lv[r]);
}

extern "C" void kernel_launch(void* const* d_in, const int* in_sizes, int n_in,
                              void* d_out, int out_size, void* d_ws, size_t ws_size,
                              hipStream_t stream) {
  const float* nodes = (const float*)d_in[0];
  const float* pos   = (const float*)d_in[1];
  const float* rot   = (const float*)d_in[2];
  const float* w_n   = (const float*)d_in[3];
  const float* b_n   = (const float*)d_in[4];
  const float* w_p   = (const float*)d_in[5];
  const float* b_p   = (const float*)d_in[6];
  const float* w_r   = (const float*)d_in[7];
  const float* w_v   = (const float*)d_in[8];
  const float* b_v   = (const float*)d_in[9];
  float* out = (float*)d_out;

  k_zero<<<dim3((SEQ * VDIM) / 256), 256, 0, stream>>>(out);
  k_prep<<<dim3(352), 256, 0, stream>>>(nodes, w_v, w_n);
  k_posrot<<<dim3(128, 2, 2), 256, 0, stream>>>(pos, rot, w_p, b_p, w_r);
  k_proj<<<dim3(32, 56), 256, 0, stream>>>(b_v, b_n);
  k_attn<<<dim3(32, NHEAD), 256, 0, stream>>>(out);
}

// Round 11
// 168.060 us; speedup vs baseline: 8.2196x; 1.0398x over previous
//
#include <hip/hip_runtime.h>
#include <hip/hip_bf16.h>
#include <math.h>

#define SEQ 2048
#define NHEAD 24     // 3*H
#define CDIM 32
#define VDIM 128

typedef short bf16x8 __attribute__((ext_vector_type(8)));
typedef float f32x4 __attribute__((ext_vector_type(4)));

#define L2E 1.44269504088896f        // log2(e): folded into K so exp2 == exp
#define SQRT_L2E 1.20112240878645f   // sqrt(log2 e): rot logits get squared

#if __has_builtin(__builtin_amdgcn_exp2f)
#define EXP2(x) __builtin_amdgcn_exp2f(x)
#else
#define EXP2(x) exp2f(x)
#endif

// K B-frags, hi/lo split: [g][blk16(128)][part(2)][lane(64)][e(8)]
__device__ unsigned short g_kkp[(size_t)24 * 128 * 2 * 64 * 8];
// Interleaved Q+V staging source: [g][jt(32 x 64j)][frag(24)][lane(64)][e(8)]
__device__ unsigned short g_qv[(size_t)24 * 32 * 24 * 64 * 8];
// weights (w_values||w_nodes_kq rows): [fg(224*4)][part(2)][lane][e]
__device__ unsigned short g_wp[(size_t)224 * 4 * 2 * 64 * 8];
// nodes A-frags: [fg(128*4)][part(2)][lane][e]
__device__ unsigned short g_np[(size_t)128 * 4 * 2 * 64 * 8];

__device__ __forceinline__ unsigned short f2b(float x) {   // RNE f32->bf16
  union { float f; unsigned u; } v; v.f = x;
  unsigned r = v.u + 0x7FFF + ((v.u >> 16) & 1);
  return (unsigned short)(r >> 16);
}
__device__ __forceinline__ float b2f(unsigned short u) {
  union { unsigned u32; float f; } x; x.u32 = ((unsigned)u) << 16; return x.f;
}
__device__ __forceinline__ unsigned pk2(float a, float b) {  // [lo=a, hi=b] bf16 pair
  __hip_bfloat162 t = __float22bfloat162_rn(float2{a, b});
  union { __hip_bfloat162 h; unsigned u; } c; c.h = t; return c.u;
}
__device__ __forceinline__ unsigned long long pack64(const float* p) {
  return ((unsigned long long)pk2(p[2], p[3]) << 32) | pk2(p[0], p[1]);
}
__device__ __forceinline__ float bperm_f(int srclane, float v) {
  union { float f; int i; } u; u.f = v;
  u.i = __builtin_amdgcn_ds_bpermute(srclane * 4, u.i);
  return u.f;
}
// async global->LDS, 16B/lane
__device__ __forceinline__ void gld16(const unsigned short* g, unsigned short* l) {
  __builtin_amdgcn_global_load_lds(
      (const __attribute__((address_space(1))) unsigned int*)g,
      (__attribute__((address_space(3))) unsigned int*)l, 16, 0, 0);
}

// ---------- one-shot hi/lo conversion of weights + nodes into frag layouts ----------
__global__ __launch_bounds__(256) void k_prep(const float* __restrict__ nodes,
                                              const float* __restrict__ w_v,
                                              const float* __restrict__ w_n) {
  const int tid = blockIdx.x * 256 + threadIdx.x;
  const int fg = tid >> 6, lane = tid & 63;
  const int e0 = (lane >> 4) * 8;
  const float* p;
  unsigned short* dst;
  if (blockIdx.x < 224) {
    const int colblk = fg >> 2, ks = fg & 3;
    const int ocol = colblk * 16 + (lane & 15);
    const float* src = (ocol < 3072) ? (w_v + (size_t)ocol * 128)
                                     : (w_n + (size_t)(ocol - 3072) * 128);
    p = src + ks * 32 + e0;
    dst = g_wp + (size_t)fg * 1024;
  } else {
    const int fg2 = fg - 224 * 4;        // 0..511
    const int rowblk = fg2 >> 2, ks = fg2 & 3;
    p = nodes + (size_t)(rowblk * 16 + (lane & 15)) * 128 + ks * 32 + e0;
    dst = g_np + (size_t)fg2 * 1024;
  }
  float4 f0 = *(const float4*)p;
  float4 f1 = *(const float4*)(p + 4);
  float ff[8] = {f0.x, f0.y, f0.z, f0.w, f1.x, f1.y, f1.z, f1.w};
  bf16x8 hi, lo;
#pragma unroll
  for (int e = 0; e < 8; ++e) {
    unsigned short h2 = f2b(ff[e]);
    hi[e] = (short)h2;
    lo[e] = (short)f2b(ff[e] - b2f(h2));
  }
  *(bf16x8*)(dst + (size_t)lane * 8) = hi;          // part 0
  *(bf16x8*)(dst + 512 + (size_t)lane * 8) = lo;    // part 1
}

// ---------- fused MFMA projection (validated round 10) ----------
__global__ __launch_bounds__(256) void k_proj(const float* __restrict__ b_v,
                                              const float* __restrict__ b_n) {
  const int jt = blockIdx.x;          // 64-row tile
  const int bo = blockIdx.y;          // 64-col tile
  const bool is_kq = bo >= 48;
  const float* bsrc = is_kq ? b_n : b_v;
  const int o0b = is_kq ? (bo - 48) * 64 : bo * 64;
  const int tx = threadIdx.x;
  const int w = tx >> 6, lane = tx & 63;
  const int m = lane & 15, quad = lane >> 4;

  __shared__ __align__(16) unsigned short bst[32][64][8];   // 32 KB
  __shared__ __align__(16) float res[4][64][20];

  const unsigned short* wp = g_wp + ((size_t)bo * 32 + w * 8) * 512 + (size_t)lane * 8;
#pragma unroll
  for (int s = 0; s < 8; ++s)
    gld16(wp + s * 512, &bst[w * 8 + s][0][0]);

  bf16x8 ah[4], al[4];
  const unsigned short* np = g_np + (size_t)(jt * 4 + w) * 4096 + (size_t)lane * 8;
#pragma unroll
  for (int ks = 0; ks < 4; ++ks) {
    ah[ks] = *(const bf16x8*)(np + ks * 1024);
    al[ks] = *(const bf16x8*)(np + ks * 1024 + 512);
  }
  __syncthreads();

  f32x4 C[4];
#pragma unroll
  for (int ob = 0; ob < 4; ++ob) {
    f32x4 acc = {0.f, 0.f, 0.f, 0.f};
#pragma unroll
    for (int ks = 0; ks < 4; ++ks) {
      bf16x8 bh = *(const bf16x8*)&bst[ob * 8 + ks * 2][lane][0];
      bf16x8 bl = *(const bf16x8*)&bst[ob * 8 + ks * 2 + 1][lane][0];
      acc = __builtin_amdgcn_mfma_f32_16x16x32_bf16(ah[ks], bh, acc, 0, 0, 0);
      acc = __builtin_amdgcn_mfma_f32_16x16x32_bf16(al[ks], bh, acc, 0, 0, 0);
      acc = __builtin_amdgcn_mfma_f32_16x16x32_bf16(ah[ks], bl, acc, 0, 0, 0);
    }
    C[ob] = acc;
  }
#pragma unroll
  for (int ob = 0; ob < 4; ++ob) {
    float bias = bsrc[o0b + ob * 16 + m];
#pragma unroll
    for (int r = 0; r < 4; ++r)
      res[w][ob * 16 + m][quad * 4 + r] = C[ob][r] + bias;
  }
  if (!is_kq) {
    const int g = bo >> 1, dbb = (bo & 1) * 4;
    const int jc = w >> 1, khb = (w & 1) * 2;
    const int rowq = quad;
#pragma unroll
    for (int oct = 0; oct < 2; ++oct) {
      f32x4 v0 = *(const f32x4*)&res[w][rowq * 16 + m][oct * 8];
      f32x4 v1 = *(const f32x4*)&res[w][rowq * 16 + m][oct * 8 + 4];
      bf16x8 pk;
#pragma unroll
      for (int e = 0; e < 4; ++e) {
        pk[e]     = (short)f2b(v0[e]);
        pk[4 + e] = (short)f2b(v1[e]);
      }
      ((bf16x8*)g_qv)[(((size_t)g * 32 + jt) * 24 + 8 + jc * 8 + dbb + rowq) * 64
                      + (khb + oct) * 16 + m] = pk;
    }
  } else {
    const int h = bo - 48;
    const int rowq = quad;
    {   // K
      bf16x8 hi, lo;
#pragma unroll
      for (int e = 0; e < 8; ++e) {
        float v = res[w][rowq * 8 + e][m] * L2E;
        unsigned short h2 = f2b(v);
        hi[e] = (short)h2;
        lo[e] = (short)f2b(v - b2f(h2));
      }
      size_t base = ((size_t)(h * 128 + jt * 4 + w) * 2) * 512 + (size_t)(rowq * 16 + m) * 8;
      *(bf16x8*)(g_kkp + base) = hi;
      *(bf16x8*)(g_kkp + base + 512) = lo;
    }
    {   // Q
      bf16x8 hi, lo;
#pragma unroll
      for (int e = 0; e < 8; ++e) {
        float v = res[w][32 + rowq * 8 + e][m];
        unsigned short h2 = f2b(v);
        hi[e] = (short)h2;
        lo[e] = (short)f2b(v - b2f(h2));
      }
      size_t base = (((size_t)h * 32 + jt) * 24 + w * 2) * 512 + (size_t)(rowq * 16 + m) * 8;
      *(bf16x8*)(g_qv + base) = hi;
      *(bf16x8*)(g_qv + base + 512) = lo;
    }
  }
}

// ---------- pos/rot k/q repack helper ----------
__device__ __forceinline__ void repack_store(const unsigned* __restrict__ res,
                                             int oh, int it16, int tx, int head_base) {
#pragma unroll
  for (int t2 = 0; t2 < 2; ++t2) {
    int cid = tx + t2 * 256;
    int hl  = cid >> 7;
    int kq  = (cid >> 6) & 1;
    int row = cid & 63;
    int m = row & 15, kb = row >> 4;
    int ob = hl * 64 + kq * 32 + kb * 8;
    bf16x8 hi, lo;
#pragma unroll
    for (int e = 0; e < 8; ++e) {
      unsigned pk = res[(ob + e) * 17 + m];
      hi[e] = (short)(pk >> 16);
      lo[e] = (short)(pk & 0xffff);
    }
    int gh = head_base + oh * 4 + hl;
    if (kq == 0) {
      size_t base = ((size_t)(gh * 128 + it16) * 2) * 512 + (size_t)row * 8;
      *(bf16x8*)(g_kkp + base) = hi;
      *(bf16x8*)(g_kkp + base + 512) = lo;
    } else {
      int jt = it16 >> 2, jb = it16 & 3;
      size_t base = (((size_t)gh * 32 + jt) * 24 + jb * 2) * 512 + (size_t)row * 8;
      *(bf16x8*)(g_qv + base) = hi;
      *(bf16x8*)(g_qv + base + 512) = lo;
    }
  }
}

// grid (128, 2, 2): z = 0 pos (heads 8..15), 1 rot (heads 16..23)
__global__ __launch_bounds__(256) void k_posrot(const float* __restrict__ pos,
                                                const float* __restrict__ rot,
                                                const float* __restrict__ w_p,
                                                const float* __restrict__ b_p,
                                                const float* __restrict__ w_r) {
  const int it16 = blockIdx.x;
  const int oh   = blockIdx.y;
  const int br   = blockIdx.z;
  const int tx = threadIdx.x;
  const int i0 = it16 * 16;

  __shared__ float pf_sh[16][8];
  __shared__ float rr_sh[16][4];
  __shared__ unsigned res[256 * 17];

  if (br == 0) {
    if (tx < 48) {
      int r = tx / 3, t = tx - r * 3;
      float p = pos[(i0 + r) * 3 + t];
      pf_sh[r][t]     = cosf(6.283185307179586f * p);
      pf_sh[r][t + 3] = sinf(6.283185307179586f * p);
    }
  } else {
    if (tx < 64) {
      int r = tx >> 2, t = tx & 3;
      rr_sh[r][t] = rot[(i0 + r) * 4 + t];
    }
  }
  __syncthreads();

  const int og = tx & 63, ig = tx >> 6;

  if (br == 0) {
#pragma unroll
    for (int oo = 0; oo < 4; ++oo) {
      int o = oh * 256 + oo * 64 + og;
      float bb = b_p[o];
      float w0 = w_p[o * 6 + 0], w1 = w_p[o * 6 + 1], w2 = w_p[o * 6 + 2];
      float w3 = w_p[o * 6 + 3], w4 = w_p[o * 6 + 4], w5 = w_p[o * 6 + 5];
      float sc = ((o & 63) < 32) ? L2E : 1.f;
#pragma unroll
      for (int ii = 0; ii < 4; ++ii) {
        int i = ig * 4 + ii;
        float v = bb + pf_sh[i][0] * w0 + pf_sh[i][1] * w1 + pf_sh[i][2] * w2
                     + pf_sh[i][3] * w3 + pf_sh[i][4] * w4 + pf_sh[i][5] * w5;
        v *= sc;
        unsigned short hi = f2b(v);
        unsigned short lo = f2b(v - b2f(hi));
        res[(oo * 64 + og) * 17 + i] = ((unsigned)hi << 16) | lo;
      }
    }
  } else {
#pragma unroll
    for (int oo = 0; oo < 4; ++oo) {
      int o = oh * 256 + oo * 64 + og;
      float w0 = w_r[o * 4 + 0], w1 = w_r[o * 4 + 1], w2 = w_r[o * 4 + 2], w3 = w_r[o * 4 + 3];
      float sc = ((o & 63) < 32) ? SQRT_L2E : 1.f;
#pragma unroll
      for (int ii = 0; ii < 4; ++ii) {
        int i = ig * 4 + ii;
        float v = (rr_sh[i][0] * w0 + rr_sh[i][1] * w1 + rr_sh[i][2] * w2 + rr_sh[i][3] * w3) * sc;
        unsigned short hi = f2b(v);
        unsigned short lo = f2b(v - b2f(hi));
        res[(oo * 64 + og) * 17 + i] = ((unsigned)hi << 16) | lo;
      }
    }
  }
  __syncthreads();
  repack_store(res, oh, it16, tx, 8 + br * 8);
}

// ---------- zero output ----------
__global__ __launch_bounds__(256) void k_zero(float* __restrict__ out) {
  out[blockIdx.x * 256 + threadIdx.x] = 0.f;
}

// ---------- MFMA flash attention: PV deferred by one iter, 3 blocks/CU ----------
__global__ __launch_bounds__(256, 3) void k_attn(float* __restrict__ out) {
  const int it = blockIdx.x;            // 0..31
  const int g  = blockIdx.y;            // 0..23
  const int tx = threadIdx.x;
  const int w = tx >> 6, lane = tx & 63;
  const int quad = lane >> 4, n = lane & 15;
  const int iblk = it * 4 + w;

  __shared__ __align__(16) unsigned short stage[2][24][64][8];   // 48 KB
  __shared__ __align__(16) unsigned long long p_lds[4][64][2];   // 4 KB  (total 52 KB -> 3 blocks/CU)

  const bf16x8* kp = (const bf16x8*)g_kkp + (size_t)(g * 128 + iblk) * 2 * 64;
  const bf16x8 khi = kp[lane], klo = kp[64 + lane];

  f32x4 oacc[8];
#pragma unroll
  for (int db = 0; db < 8; ++db)
#pragma unroll
    for (int r = 0; r < 4; ++r) oacc[db][r] = 0.f;

  float m_run = -3.0e38f, l_part = 0.f;
  const bool is_rot = (g >= 16);
  const int pin = (lane & 56) | ((lane ^ (lane >> 3)) & 7);
  const int wrow0 = (quad >> 1) * 16 + n;
  const int wrow1 = wrow0 + 32;
  const int pr0 = (wrow0 & 56) | ((wrow0 ^ (wrow0 >> 3)) & 7);
  const int pr1 = (wrow1 & 56) | ((wrow1 ^ (wrow1 >> 3)) & 7);
  const int whalf = quad & 1;

  const unsigned short* qv = g_qv + ((size_t)g * 32 * 24 + w * 6) * 512 + (size_t)lane * 8;

#define STG(nb)                                          \
  { gld16(qv,             &stage[nb][w * 6 + 0][0][0]);  \
    gld16(qv + 512,       &stage[nb][w * 6 + 1][0][0]);  \
    gld16(qv + 1024,      &stage[nb][w * 6 + 2][0][0]);  \
    gld16(qv + 1536,      &stage[nb][w * 6 + 3][0][0]);  \
    gld16(qv + 2048,      &stage[nb][w * 6 + 4][0][0]);  \
    gld16(qv + 2560,      &stage[nb][w * 6 + 5][0][0]); }

  STG(0)

  bf16x8 a0 = {}, a1 = {};       // P(jt-1) A-frags (live across iterations)
  bf16x8 vprev[16];              // V(jt-1) B-frags (live across iterations)

  for (int jt = 0; jt < 32; ++jt) {
    const int buf = jt & 1;
    __syncthreads();                       // stage[buf] ready; buf^1 consumers done (reg-read last iter)

    // --- deferred PV(jt-1): all operands in registers, feeds matrix pipe immediately
    if (jt) {
#pragma unroll
      for (int db = 0; db < 8; ++db)
        oacc[db] = __builtin_amdgcn_mfma_f32_16x16x32_bf16(a0, vprev[db], oacc[db], 0, 0, 0);
#pragma unroll
      for (int db = 0; db < 8; ++db)
        oacc[db] = __builtin_amdgcn_mfma_f32_16x16x32_bf16(a1, vprev[8 + db], oacc[db], 0, 0, 0);
    }

    qv += 24 * 512;
    if (jt < 31) STG(buf ^ 1)              // async prefetch into buf^1 (safe: reg-consumed)

    const bf16x8* st = (const bf16x8*)&stage[buf][0][0][0];
    // --- S^T = Q·K^T (split bf16 hi/lo)
    f32x4 S[4];
#pragma unroll
    for (int jb = 0; jb < 4; ++jb) {
      bf16x8 qh = st[(jb * 2) * 64 + lane], ql = st[(jb * 2 + 1) * 64 + lane];
      f32x4 a = {0.f, 0.f, 0.f, 0.f};
      a = __builtin_amdgcn_mfma_f32_16x16x32_bf16(qh, khi, a, 0, 0, 0);
      a = __builtin_amdgcn_mfma_f32_16x16x32_bf16(ql, khi, a, 0, 0, 0);
      a = __builtin_amdgcn_mfma_f32_16x16x32_bf16(qh, klo, a, 0, 0, 0);
      S[jb] = a;
    }
    if (is_rot) {
#pragma unroll
      for (int jb = 0; jb < 4; ++jb)
#pragma unroll
        for (int r = 0; r < 4; ++r) S[jb][r] *= S[jb][r];
    }
    // --- lane-local max; cross-lane reduce only when guard fires
    float mloc = S[0][0];
#pragma unroll
    for (int jb = 0; jb < 4; ++jb)
#pragma unroll
      for (int r = 0; r < 4; ++r) mloc = fmaxf(mloc, S[jb][r]);
    if (__ballot(mloc > m_run)) {          // rare after warm-up
      float mb = fmaxf(mloc, __shfl_xor(mloc, 16));
      mb = fmaxf(mb, __shfl_xor(mb, 32));
      float m_new = fmaxf(m_run, mb);
      float alpha = EXP2(m_run - m_new);
      m_run = m_new;
      l_part *= alpha;
      f32x4 av;
#pragma unroll
      for (int r = 0; r < 4; ++r) av[r] = bperm_f(quad * 4 + r, alpha);
#pragma unroll
      for (int db = 0; db < 8; ++db) {
        oacc[db][0] *= av[0]; oacc[db][1] *= av[1];
        oacc[db][2] *= av[2]; oacc[db][3] *= av[3];
      }
    }
    // --- P = 2^(S - m); per-lane l partial (reduce deferred to epilogue)
    float p[4][4];
#pragma unroll
    for (int jb = 0; jb < 4; ++jb)
#pragma unroll
      for (int r = 0; r < 4; ++r) {
        p[jb][r] = EXP2(S[jb][r] - m_run);
        l_part += p[jb][r];
      }
    // --- pack P into A-frags via p_lds (wave-local, in-order DS); consumed NEXT iter
    p_lds[w][pr0][whalf] = pack64(p[0]);
    p_lds[w][pr1][whalf] = pack64(p[1]);
    a0 = *(const bf16x8*)&p_lds[w][pin][0];
    p_lds[w][pr0][whalf] = pack64(p[2]);
    p_lds[w][pr1][whalf] = pack64(p[3]);
    a1 = *(const bf16x8*)&p_lds[w][pin][0];
    // --- read V(jt) into regs for next iter's deferred PV
#pragma unroll
    for (int f = 0; f < 16; ++f) vprev[f] = st[(8 + f) * 64 + lane];
  }
  // --- final PV(31)
#pragma unroll
  for (int db = 0; db < 8; ++db)
    oacc[db] = __builtin_amdgcn_mfma_f32_16x16x32_bf16(a0, vprev[db], oacc[db], 0, 0, 0);
#pragma unroll
  for (int db = 0; db < 8; ++db)
    oacc[db] = __builtin_amdgcn_mfma_f32_16x16x32_bf16(a1, vprev[8 + db], oacc[db], 0, 0, 0);

  // --- epilogue: deferred l reduction, column->row broadcast, scaled atomics
  float l = l_part;
  l += __shfl_xor(l, 16);
  l += __shfl_xor(l, 32);
  float linv = 1.f / l;
  f32x4 lv;
#pragma unroll
  for (int r = 0; r < 4; ++r) lv[r] = bperm_f(quad * 4 + r, linv);
  const int ibase = it * 64 + w * 16 + quad * 4;
#pragma unroll
  for (int db = 0; db < 8; ++db)
#pragma unroll
    for (int r = 0; r < 4; ++r)
      atomicAdd(&out[(size_t)(ibase + r) * VDIM + db * 16 + n], oacc[db][r] * lv[r]);
}

extern "C" void kernel_launch(void* const* d_in, const int* in_sizes, int n_in,
                              void* d_out, int out_size, void* d_ws, size_t ws_size,
                              hipStream_t stream) {
  const float* nodes = (const float*)d_in[0];
  const float* pos   = (const float*)d_in[1];
  const float* rot   = (const float*)d_in[2];
  const float* w_n   = (const float*)d_in[3];
  const float* b_n   = (const float*)d_in[4];
  const float* w_p   = (const float*)d_in[5];
  const float* b_p   = (const float*)d_in[6];
  const float* w_r   = (const float*)d_in[7];
  const float* w_v   = (const float*)d_in[8];
  const float* b_v   = (const float*)d_in[9];
  float* out = (float*)d_out;

  k_zero<<<dim3((SEQ * VDIM) / 256), 256, 0, stream>>>(out);
  k_prep<<<dim3(352), 256, 0, stream>>>(nodes, w_v, w_n);
  k_posrot<<<dim3(128, 2, 2), 256, 0, stream>>>(pos, rot, w_p, b_p, w_r);
  k_proj<<<dim3(32, 56), 256, 0, stream>>>(b_v, b_n);
  k_attn<<<dim3(32, NHEAD), 256, 0, stream>>>(out);
}